// Round 10
// baseline (508.132 us; speedup 1.0000x reference)
//
#include <hip/hip_runtime.h>
#include <hip/hip_bf16.h>

// MambaFeatureEnhancer — B=2, C=128, L=4096, d_inner=256, N=16, R=8, 2 layers. All I/O fp32.
// All GEMMs bf16 MFMA (fp32 accum). dtproj folded into xproj (Wcomb, padded to 384 rows);
// LN fused into in_proj/ffn1; outc fused with output transpose+residual; scan_phase2 inlined
// into phase3 (per-block prefix). Scan: NC=128 chunks, 4 n-states/lane.

#define LSEQ 4096
#define BLC  8192      // B * L
#define NC   128       // scan chunks
#define CHK  32        // chunk length
#define NCH  8192      // B * d_inner * N state channels

typedef __attribute__((ext_vector_type(4))) float f32x4;
typedef __attribute__((ext_vector_type(8))) short s16x8;

__device__ __forceinline__ unsigned short f2bu(float f) {   // fp32 -> bf16 bits, RNE
    unsigned u = __float_as_uint(f);
    return (unsigned short)((u + 0x7fffu + ((u >> 16) & 1u)) >> 16);
}
__device__ __forceinline__ float softplus_f(float v) {
    return (v > 0.f) ? v + log1pf(expf(-v)) : log1pf(expf(v));
}

// ---------------------------------------------------------------- input transpose (B,C,L)->(B,L,C)
__global__ __launch_bounds__(256) void transpose_kernel(
    const float* __restrict__ in_, float* __restrict__ out_, int R, int Cc)
{
    __shared__ float tile[32][33];
    size_t boff = (size_t)blockIdx.z * R * Cc;
    int r0 = blockIdx.y * 32, c0 = blockIdx.x * 32;
    int tx = threadIdx.x, ty = threadIdx.y;   // block (32,8)
#pragma unroll
    for (int j = 0; j < 4; ++j)
        tile[ty + j * 8][tx] = in_[boff + (size_t)(r0 + ty + j * 8) * Cc + (c0 + tx)];
    __syncthreads();
#pragma unroll
    for (int j = 0; j < 4; ++j)
        out_[boff + (size_t)(c0 + ty + j * 8) * R + (r0 + tx)] = tile[tx][ty + j * 8];
}

// ---------------------------------------------------------------- Wcomb precompute (2 x 384 x 256)
// row<256: dt-combined; 256..287: B/C rows of xproj; 288..383: zero pad.
__global__ __launch_bounds__(256) void build_wcomb(
    const float* __restrict__ xproj_w, const float* __restrict__ dtproj_w,
    float* __restrict__ wc)
{
    int i = blockIdx.x * 256 + threadIdx.x;     // 0 .. 2*384*256-1
    int layer = i / 98304;
    int rem   = i - layer * 98304;
    int row = rem >> 8, col = rem & 255;
    const float* xp = xproj_w + layer * 10240;
    float v = 0.f;
    if (row < 256) {
        const float* dw = dtproj_w + layer * 2048 + row * 8;
#pragma unroll
        for (int r = 0; r < 8; ++r) v = fmaf(dw[r], xp[r * 256 + col], v);
    } else if (row < 288) {
        v = xp[(8 + row - 256) * 256 + col];
    }
    wc[i] = v;
}

// ---------------------------------------------------------------- bf16 MFMA GEMM (generic)
// Y[m,n] = act( sum_k X[m,k]*W[n,k] + bias[n] ) (+ res[m,n]).
// EPI (K=256): X[m,k] := (X[m,k] + pu[m,k]*pD[k]) * silu(pz[m,k]) during staging.
// OUTT: write transposed out[b][n][l] = v + res[b][n][l]  (res = original x).
template<int BM, int BN, int ACT, bool BIAS, bool RES, bool EPI, bool OUTT>
__global__ __launch_bounds__(256) void mgemm(
    const float* __restrict__ X, const float* __restrict__ W,
    const float* __restrict__ bias, const float* __restrict__ res,
    const float* __restrict__ pu, const float* __restrict__ pz,
    const float* __restrict__ pD,
    float* __restrict__ Y, int N, int K)
{
    constexpr int MF = BM / 32, NF = BN / 32;
    __shared__ __align__(16) unsigned short Xs[BM * 64];
    __shared__ __align__(16) unsigned short Ws[BN * 64];
    int tid  = threadIdx.x;
    int lane = tid & 63;
    int wave = tid >> 6;
    int wm = wave >> 1, wn = wave & 1;
    int l15 = lane & 15, l4 = lane >> 4;
    int bm = blockIdx.x * BM, bn = blockIdx.y * BN;
    f32x4 acc[MF][NF] = {};
    int q  = tid & 15;
    int r0 = tid >> 4;

    for (int k0 = 0; k0 < K; k0 += 64) {
        __syncthreads();
#pragma unroll
        for (int p = 0; p < BM / 16; ++p) {
            int row = r0 + p * 16;
            size_t gi = (size_t)(bm + row) * K + k0 + q * 4;
            float4 v = *(const float4*)&X[gi];
            if (EPI) {
                float4 u4 = *(const float4*)&pu[gi];
                float4 z4 = *(const float4*)&pz[gi];
                float4 D4 = *(const float4*)&pD[k0 + q * 4];
                v.x = fmaf(u4.x, D4.x, v.x) * (z4.x / (1.f + __expf(-z4.x)));
                v.y = fmaf(u4.y, D4.y, v.y) * (z4.y / (1.f + __expf(-z4.y)));
                v.z = fmaf(u4.z, D4.z, v.z) * (z4.z / (1.f + __expf(-z4.z)));
                v.w = fmaf(u4.w, D4.w, v.w) * (z4.w / (1.f + __expf(-z4.w)));
            }
            unsigned lo = f2bu(v.x) | ((unsigned)f2bu(v.y) << 16);
            unsigned hi = f2bu(v.z) | ((unsigned)f2bu(v.w) << 16);
            int off = (row * 128 + q * 8) ^ ((row & 7) << 4);
            *(uint2*)((char*)Xs + off) = make_uint2(lo, hi);
        }
#pragma unroll
        for (int p = 0; p < BN / 16; ++p) {
            int row = r0 + p * 16;
            float4 v = *(const float4*)&W[(size_t)(bn + row) * K + k0 + q * 4];
            unsigned lo = f2bu(v.x) | ((unsigned)f2bu(v.y) << 16);
            unsigned hi = f2bu(v.z) | ((unsigned)f2bu(v.w) << 16);
            int off = (row * 128 + q * 8) ^ ((row & 7) << 4);
            *(uint2*)((char*)Ws + off) = make_uint2(lo, hi);
        }
        __syncthreads();
#pragma unroll
        for (int ks = 0; ks < 2; ++ks) {
            s16x8 a[MF], b[NF];
#pragma unroll
            for (int mf = 0; mf < MF; ++mf) {
                int row = wm * (BM / 2) + mf * 16 + l15;
                int off = (row * 128 + (ks * 32 + l4 * 8) * 2) ^ ((row & 7) << 4);
                a[mf] = *(const s16x8*)((const char*)Xs + off);
            }
#pragma unroll
            for (int nf = 0; nf < NF; ++nf) {
                int row = wn * (BN / 2) + nf * 16 + l15;
                int off = (row * 128 + (ks * 32 + l4 * 8) * 2) ^ ((row & 7) << 4);
                b[nf] = *(const s16x8*)((const char*)Ws + off);
            }
#pragma unroll
            for (int mf = 0; mf < MF; ++mf)
#pragma unroll
                for (int nf = 0; nf < NF; ++nf)
                    acc[mf][nf] = __builtin_amdgcn_mfma_f32_16x16x32_bf16(
                        a[mf], b[nf], acc[mf][nf], 0, 0, 0);
        }
    }

#pragma unroll
    for (int mf = 0; mf < MF; ++mf) {
#pragma unroll
        for (int nf = 0; nf < NF; ++nf) {
            int col   = bn + wn * (BN / 2) + nf * 16 + l15;
            int rbase = bm + wm * (BM / 2) + mf * 16 + l4 * 4;
            float bv = BIAS ? bias[col] : 0.f;
            if (OUTT) {
                int bi = rbase >> 12;
                int l  = rbase & 4095;
                size_t ob = (size_t)bi * 524288 + (size_t)col * 4096 + l;
#pragma unroll
                for (int r = 0; r < 4; ++r)
                    Y[ob + r] = acc[mf][nf][r] + bv + res[ob + r];
            } else {
#pragma unroll
                for (int r = 0; r < 4; ++r) {
                    float v = acc[mf][nf][r] + bv;
                    if (ACT == 2) v = 0.5f * v * (1.f + erff(v * 0.70710678118654752f));
                    size_t o = (size_t)(rbase + r) * N + col;
                    if (RES) v += res[o];
                    Y[o] = v;
                }
            }
        }
    }
}

// ---------------------------------------------------------------- LN-fused GEMM (BM=128, BN=128, K=128)
// X = t (BLC x 128); LN per row fused into bf16 staging. SPLIT: N=512 -> Y(0..255)/Y2(256..511).
template<int ACT, bool BIAS, bool SPLIT>
__global__ __launch_bounds__(256) void mgemm_ln(
    const float* __restrict__ X,
    const float* __restrict__ lng, const float* __restrict__ lnb,
    const float* __restrict__ W, const float* __restrict__ bias,
    float* __restrict__ Y, float* __restrict__ Y2, int N)
{
    __shared__ __align__(16) unsigned short Xs[128 * 128];   // 32 KB
    __shared__ __align__(16) unsigned short Ws[128 * 64];    // 16 KB
    int tid  = threadIdx.x;
    int lane = tid & 63;
    int wave = tid >> 6;
    int wm = wave >> 1, wn = wave & 1;
    int l15 = lane & 15, l4 = lane >> 4;
    int bm = blockIdx.x * 128, bn = blockIdx.y * 128;

    // ---- LN + quantize X tile (128 rows x 128 cols)
    int rsub = lane >> 4;   // 0..3
    int cg   = lane & 15;   // 0..15, 8 cols each
    float4 ga = *(const float4*)&lng[cg * 8], gb = *(const float4*)&lng[cg * 8 + 4];
    float4 ba = *(const float4*)&lnb[cg * 8], bb2 = *(const float4*)&lnb[cg * 8 + 4];
#pragma unroll 2
    for (int it = 0; it < 8; ++it) {
        int row = wave * 32 + it * 4 + rsub;
        const float* xr = X + (size_t)(bm + row) * 128 + cg * 8;
        float4 xa = *(const float4*)xr;
        float4 xb = *(const float4*)(xr + 4);
        float s = xa.x + xa.y + xa.z + xa.w + xb.x + xb.y + xb.z + xb.w;
        float q = xa.x*xa.x + xa.y*xa.y + xa.z*xa.z + xa.w*xa.w
                + xb.x*xb.x + xb.y*xb.y + xb.z*xb.z + xb.w*xb.w;
        s += __shfl_xor(s, 1, 16); q += __shfl_xor(q, 1, 16);
        s += __shfl_xor(s, 2, 16); q += __shfl_xor(q, 2, 16);
        s += __shfl_xor(s, 4, 16); q += __shfl_xor(q, 4, 16);
        s += __shfl_xor(s, 8, 16); q += __shfl_xor(q, 8, 16);
        float mean = s * 0.0078125f;
        float var  = fmaf(-mean, mean, q * 0.0078125f);
        float rstd = rsqrtf(var + 1e-5f);
        float o0 = fmaf((xa.x - mean) * rstd, ga.x, ba.x);
        float o1 = fmaf((xa.y - mean) * rstd, ga.y, ba.y);
        float o2 = fmaf((xa.z - mean) * rstd, ga.z, ba.z);
        float o3 = fmaf((xa.w - mean) * rstd, ga.w, ba.w);
        float o4 = fmaf((xb.x - mean) * rstd, gb.x, bb2.x);
        float o5 = fmaf((xb.y - mean) * rstd, gb.y, bb2.y);
        float o6 = fmaf((xb.z - mean) * rstd, gb.z, bb2.z);
        float o7 = fmaf((xb.w - mean) * rstd, gb.w, bb2.w);
        uint4 wv;
        wv.x = f2bu(o0) | ((unsigned)f2bu(o1) << 16);
        wv.y = f2bu(o2) | ((unsigned)f2bu(o3) << 16);
        wv.z = f2bu(o4) | ((unsigned)f2bu(o5) << 16);
        wv.w = f2bu(o6) | ((unsigned)f2bu(o7) << 16);
        int off = (row * 256 + cg * 16) ^ ((row & 7) << 4);
        *(uint4*)((char*)Xs + off) = wv;
    }

    f32x4 acc[4][4] = {};
    int q4 = tid & 15, r0 = tid >> 4;
    for (int k0 = 0; k0 < 128; k0 += 64) {
#pragma unroll
        for (int p = 0; p < 8; ++p) {
            int row = r0 + p * 16;
            float4 v = *(const float4*)&W[(size_t)(bn + row) * 128 + k0 + q4 * 4];
            unsigned lo = f2bu(v.x) | ((unsigned)f2bu(v.y) << 16);
            unsigned hi = f2bu(v.z) | ((unsigned)f2bu(v.w) << 16);
            int off = (row * 128 + q4 * 8) ^ ((row & 7) << 4);
            *(uint2*)((char*)Ws + off) = make_uint2(lo, hi);
        }
        __syncthreads();
#pragma unroll
        for (int ks = 0; ks < 2; ++ks) {
            s16x8 a[4], b[4];
#pragma unroll
            for (int mf = 0; mf < 4; ++mf) {
                int row = wm * 64 + mf * 16 + l15;
                int off = (row * 256 + (k0 + ks * 32 + l4 * 8) * 2) ^ ((row & 7) << 4);
                a[mf] = *(const s16x8*)((const char*)Xs + off);
            }
#pragma unroll
            for (int nf = 0; nf < 4; ++nf) {
                int row = wn * 64 + nf * 16 + l15;
                int off = (row * 128 + (ks * 32 + l4 * 8) * 2) ^ ((row & 7) << 4);
                b[nf] = *(const s16x8*)((const char*)Ws + off);
            }
#pragma unroll
            for (int mf = 0; mf < 4; ++mf)
#pragma unroll
                for (int nf = 0; nf < 4; ++nf)
                    acc[mf][nf] = __builtin_amdgcn_mfma_f32_16x16x32_bf16(
                        a[mf], b[nf], acc[mf][nf], 0, 0, 0);
        }
        __syncthreads();
    }

#pragma unroll
    for (int mf = 0; mf < 4; ++mf) {
#pragma unroll
        for (int nf = 0; nf < 4; ++nf) {
            int col   = bn + wn * 64 + nf * 16 + l15;
            int rbase = bm + wm * 64 + mf * 16 + l4 * 4;
            float bv = BIAS ? bias[col] : 0.f;
#pragma unroll
            for (int r = 0; r < 4; ++r) {
                float v = acc[mf][nf][r] + bv;
                if (ACT == 2) v = 0.5f * v * (1.f + erff(v * 0.70710678118654752f));
                if (SPLIT) {
                    if (col < 256) Y [(size_t)(rbase + r) * 256 + col]       = v;
                    else           Y2[(size_t)(rbase + r) * 256 + col - 256] = v;
                } else {
                    Y[(size_t)(rbase + r) * N + col] = v;
                }
            }
        }
    }
}

// ---------------------------------------------------------------- dt+B/C GEMM (BM=128, BN=128, K=256)
// Blocks bn<2: dt = softplus(acc+bias) -> dtT[d][row], dtuT = dt*u.
// Block bn==2: cols 0..31 -> bct[n][row] (B rows 0..15, C rows 16..31).
__global__ __launch_bounds__(256) void mgemm_dtbc(
    const float* __restrict__ Xu, const float* __restrict__ W,
    const float* __restrict__ bias,
    float* __restrict__ dtT, float* __restrict__ dtuT, float* __restrict__ bct)
{
    __shared__ __align__(16) unsigned short Xs[128 * 64];
    __shared__ __align__(16) unsigned short Ws[128 * 64];
    int tid  = threadIdx.x;
    int lane = tid & 63;
    int wave = tid >> 6;
    int wm = wave >> 1, wn = wave & 1;
    int l15 = lane & 15, l4 = lane >> 4;
    int bm = blockIdx.x * 128, bn = blockIdx.y * 128;
    f32x4 acc[4][4] = {};
    int q  = tid & 15;
    int r0 = tid >> 4;

    for (int k0 = 0; k0 < 256; k0 += 64) {
        __syncthreads();
#pragma unroll
        for (int p = 0; p < 8; ++p) {
            int row = r0 + p * 16;
            float4 v = *(const float4*)&Xu[(size_t)(bm + row) * 256 + k0 + q * 4];
            unsigned lo = f2bu(v.x) | ((unsigned)f2bu(v.y) << 16);
            unsigned hi = f2bu(v.z) | ((unsigned)f2bu(v.w) << 16);
            int off = (row * 128 + q * 8) ^ ((row & 7) << 4);
            *(uint2*)((char*)Xs + off) = make_uint2(lo, hi);
        }
#pragma unroll
        for (int p = 0; p < 8; ++p) {
            int row = r0 + p * 16;
            float4 v = *(const float4*)&W[(size_t)(bn + row) * 256 + k0 + q * 4];
            unsigned lo = f2bu(v.x) | ((unsigned)f2bu(v.y) << 16);
            unsigned hi = f2bu(v.z) | ((unsigned)f2bu(v.w) << 16);
            int off = (row * 128 + q * 8) ^ ((row & 7) << 4);
            *(uint2*)((char*)Ws + off) = make_uint2(lo, hi);
        }
        __syncthreads();
#pragma unroll
        for (int ks = 0; ks < 2; ++ks) {
            s16x8 a[4], b[4];
#pragma unroll
            for (int mf = 0; mf < 4; ++mf) {
                int row = wm * 64 + mf * 16 + l15;
                int off = (row * 128 + (ks * 32 + l4 * 8) * 2) ^ ((row & 7) << 4);
                a[mf] = *(const s16x8*)((const char*)Xs + off);
            }
#pragma unroll
            for (int nf = 0; nf < 4; ++nf) {
                int row = wn * 64 + nf * 16 + l15;
                int off = (row * 128 + (ks * 32 + l4 * 8) * 2) ^ ((row & 7) << 4);
                b[nf] = *(const s16x8*)((const char*)Ws + off);
            }
#pragma unroll
            for (int mf = 0; mf < 4; ++mf)
#pragma unroll
                for (int nf = 0; nf < 4; ++nf)
                    acc[mf][nf] = __builtin_amdgcn_mfma_f32_16x16x32_bf16(
                        a[mf], b[nf], acc[mf][nf], 0, 0, 0);
        }
    }

    if (blockIdx.y < 2) {
#pragma unroll
        for (int mf = 0; mf < 4; ++mf) {
#pragma unroll
            for (int nf = 0; nf < 4; ++nf) {
                int col   = bn + wn * 64 + nf * 16 + l15;
                int rbase = bm + wm * 64 + mf * 16 + l4 * 4;
                float bv = bias[col];
                float4 uu;
                uu.x = Xu[(size_t)(rbase + 0) * 256 + col];
                uu.y = Xu[(size_t)(rbase + 1) * 256 + col];
                uu.z = Xu[(size_t)(rbase + 2) * 256 + col];
                uu.w = Xu[(size_t)(rbase + 3) * 256 + col];
                float v0 = softplus_f(acc[mf][nf][0] + bv);
                float v1 = softplus_f(acc[mf][nf][1] + bv);
                float v2 = softplus_f(acc[mf][nf][2] + bv);
                float v3 = softplus_f(acc[mf][nf][3] + bv);
                *(float4*)&dtT [(size_t)col * BLC + rbase] = make_float4(v0, v1, v2, v3);
                *(float4*)&dtuT[(size_t)col * BLC + rbase] =
                    make_float4(v0 * uu.x, v1 * uu.y, v2 * uu.z, v3 * uu.w);
            }
        }
    } else {
#pragma unroll
        for (int mf = 0; mf < 4; ++mf) {
#pragma unroll
            for (int nf = 0; nf < 4; ++nf) {
                int col16 = wn * 64 + nf * 16 + l15;     // valid < 32
                int rbase = bm + wm * 64 + mf * 16 + l4 * 4;
                if (col16 < 32) {
                    *(float4*)&bct[(size_t)col16 * BLC + rbase] =
                        make_float4(acc[mf][nf][0], acc[mf][nf][1],
                                    acc[mf][nf][2], acc[mf][nf][3]);
                }
            }
        }
    }
}

// ---------------------------------------------------------------- conv1d (depthwise causal k=4) + silu
__global__ __launch_bounds__(256) void conv_silu_kernel(
    const float* __restrict__ u, const float* __restrict__ cw,
    const float* __restrict__ cb, float* __restrict__ out)
{
    int i   = blockIdx.x * 256 + threadIdx.x;   // BLC * 64
    int dq  = (i & 63) << 2;
    int row = i >> 6;
    int l   = row & (LSEQ - 1);
    float4 a = *(const float4*)&cb[dq];
    float w[4][4];
#pragma unroll
    for (int e = 0; e < 4; ++e) {
        float4 we = *(const float4*)&cw[(dq + e) * 4];
        w[e][0] = we.x; w[e][1] = we.y; w[e][2] = we.z; w[e][3] = we.w;
    }
#pragma unroll
    for (int j = 0; j < 4; ++j) {
        if (l >= 3 - j) {
            const float4 v = *(const float4*)&u[(size_t)(row - 3 + j) * 256 + dq];
            a.x = fmaf(v.x, w[0][j], a.x);
            a.y = fmaf(v.y, w[1][j], a.y);
            a.z = fmaf(v.z, w[2][j], a.z);
            a.w = fmaf(v.w, w[3][j], a.w);
        }
    }
    float4 o;
    o.x = a.x / (1.f + __expf(-a.x));
    o.y = a.y / (1.f + __expf(-a.y));
    o.z = a.z / (1.f + __expf(-a.z));
    o.w = a.w / (1.f + __expf(-a.w));
    *(float4*)&out[(size_t)row * 256 + dq] = o;
}

// ---------------------------------------------------------------- chunked selective scan
// Lane owns 4 n-states of one d: g = tid&3, dloc = tid>>2. grid (4, NC, B) = 1024 blocks.
__global__ __launch_bounds__(256) void scan_phase1(
    const float* __restrict__ dtT, const float* __restrict__ dtuT,
    const float* __restrict__ bct, const float* __restrict__ A_log,
    float* __restrict__ hend, float* __restrict__ aprod)
{
    int g    = threadIdx.x & 3;
    int dloc = threadIdx.x >> 2;
    int d    = blockIdx.x * 64 + dloc;
    int c    = blockIdx.y;
    int b    = blockIdx.z;
    float4 al = *(const float4*)&A_log[d * 16 + g * 4];
    float A0 = -__expf(al.x), A1 = -__expf(al.y), A2 = -__expf(al.z), A3 = -__expf(al.w);
    int base   = d * BLC + b * LSEQ + c * CHK;
    int btbase = b * LSEQ + c * CHK;
    const float* B0p = bct + (size_t)(g * 4 + 0) * BLC + btbase;
    const float* B1p = B0p + BLC;
    const float* B2p = B1p + BLC;
    const float* B3p = B2p + BLC;
    float h0 = 0.f, h1 = 0.f, h2 = 0.f, h3 = 0.f;
    float p0 = 1.f, p1 = 1.f, p2 = 1.f, p3 = 1.f;
#pragma unroll 2
    for (int t4 = 0; t4 < CHK; t4 += 4) {
        float4 dt4 = *(const float4*)&dtT [base + t4];
        float4 du4 = *(const float4*)&dtuT[base + t4];
        float4 B0 = *(const float4*)(B0p + t4);
        float4 B1 = *(const float4*)(B1p + t4);
        float4 B2 = *(const float4*)(B2p + t4);
        float4 B3 = *(const float4*)(B3p + t4);
        float dts[4] = {dt4.x, dt4.y, dt4.z, dt4.w};
        float dus[4] = {du4.x, du4.y, du4.z, du4.w};
        float b0[4] = {B0.x, B0.y, B0.z, B0.w};
        float b1[4] = {B1.x, B1.y, B1.z, B1.w};
        float b2[4] = {B2.x, B2.y, B2.z, B2.w};
        float b3[4] = {B3.x, B3.y, B3.z, B3.w};
#pragma unroll
        for (int j = 0; j < 4; ++j) {
            float a0 = __expf(dts[j] * A0), a1 = __expf(dts[j] * A1);
            float a2 = __expf(dts[j] * A2), a3 = __expf(dts[j] * A3);
            h0 = fmaf(a0, h0, dus[j] * b0[j]); p0 *= a0;
            h1 = fmaf(a1, h1, dus[j] * b1[j]); p1 *= a1;
            h2 = fmaf(a2, h2, dus[j] * b2[j]); p2 *= a2;
            h3 = fmaf(a3, h3, dus[j] * b3[j]); p3 *= a3;
        }
    }
    int ch = (b * 256 + d) * 16 + g * 4;
    *(float4*)&hend [c * NCH + ch] = make_float4(h0, h1, h2, h3);
    *(float4*)&aprod[c * NCH + ch] = make_float4(p0, p1, p2, p3);
}

// Phase 3: inline h0 prefix over chunks < c, then recompute + C-dot + write y[row][d].
__global__ __launch_bounds__(256) void scan_phase3(
    const float* __restrict__ dtT, const float* __restrict__ dtuT,
    const float* __restrict__ bct, const float* __restrict__ A_log,
    const float* __restrict__ hend, const float* __restrict__ aprod,
    float* __restrict__ y)
{
    int g    = threadIdx.x & 3;
    int dloc = threadIdx.x >> 2;
    int d    = blockIdx.x * 64 + dloc;
    int c    = blockIdx.y;
    int b    = blockIdx.z;
    float4 al = *(const float4*)&A_log[d * 16 + g * 4];
    float A0 = -__expf(al.x), A1 = -__expf(al.y), A2 = -__expf(al.z), A3 = -__expf(al.w);
    int ch = (b * 256 + d) * 16 + g * 4;
    // inline prefix: h0..h3 = state at start of chunk c
    float h0 = 0.f, h1 = 0.f, h2 = 0.f, h3 = 0.f;
    for (int cc = 0; cc < c; ++cc) {
        float4 ap = *(const float4*)&aprod[cc * NCH + ch];
        float4 he = *(const float4*)&hend [cc * NCH + ch];
        h0 = fmaf(ap.x, h0, he.x);
        h1 = fmaf(ap.y, h1, he.y);
        h2 = fmaf(ap.z, h2, he.z);
        h3 = fmaf(ap.w, h3, he.w);
    }
    int base = d * BLC + b * LSEQ + c * CHK;
    int row0 = b * LSEQ + c * CHK;
    const float* B0p = bct + (size_t)(g * 4 + 0) * BLC + row0;
    const float* B1p = B0p + BLC;
    const float* B2p = B1p + BLC;
    const float* B3p = B2p + BLC;
    const float* C0p = bct + (size_t)(16 + g * 4) * BLC + row0;
    const float* C1p = C0p + BLC;
    const float* C2p = C1p + BLC;
    const float* C3p = C2p + BLC;
#pragma unroll 2
    for (int t4 = 0; t4 < CHK; t4 += 4) {
        float4 dt4 = *(const float4*)&dtT [base + t4];
        float4 du4 = *(const float4*)&dtuT[base + t4];
        float4 B0 = *(const float4*)(B0p + t4);
        float4 B1 = *(const float4*)(B1p + t4);
        float4 B2 = *(const float4*)(B2p + t4);
        float4 B3 = *(const float4*)(B3p + t4);
        float4 C0 = *(const float4*)(C0p + t4);
        float4 C1 = *(const float4*)(C1p + t4);
        float4 C2 = *(const float4*)(C2p + t4);
        float4 C3 = *(const float4*)(C3p + t4);
        float dts[4] = {dt4.x, dt4.y, dt4.z, dt4.w};
        float dus[4] = {du4.x, du4.y, du4.z, du4.w};
        float b0[4] = {B0.x, B0.y, B0.z, B0.w};
        float b1[4] = {B1.x, B1.y, B1.z, B1.w};
        float b2[4] = {B2.x, B2.y, B2.z, B2.w};
        float b3[4] = {B3.x, B3.y, B3.z, B3.w};
        float c0[4] = {C0.x, C0.y, C0.z, C0.w};
        float c1[4] = {C1.x, C1.y, C1.z, C1.w};
        float c2[4] = {C2.x, C2.y, C2.z, C2.w};
        float c3[4] = {C3.x, C3.y, C3.z, C3.w};
#pragma unroll
        for (int j = 0; j < 4; ++j) {
            float a0 = __expf(dts[j] * A0), a1 = __expf(dts[j] * A1);
            float a2 = __expf(dts[j] * A2), a3 = __expf(dts[j] * A3);
            h0 = fmaf(a0, h0, dus[j] * b0[j]);
            h1 = fmaf(a1, h1, dus[j] * b1[j]);
            h2 = fmaf(a2, h2, dus[j] * b2[j]);
            h3 = fmaf(a3, h3, dus[j] * b3[j]);
            float p = h0 * c0[j];
            p = fmaf(h1, c1[j], p);
            p = fmaf(h2, c2[j], p);
            p = fmaf(h3, c3[j], p);
            p += __shfl_xor(p, 1);
            p += __shfl_xor(p, 2);
            if (g == 0) y[(size_t)(row0 + t4 + j) * 256 + d] = p;
        }
    }
}

// ---------------------------------------------------------------- launch
extern "C" void kernel_launch(void* const* d_in, const int* in_sizes, int n_in,
                              void* d_out, int out_size, void* d_ws, size_t ws_size,
                              hipStream_t stream)
{
    const float* x        = (const float*)d_in[0];
    const float* embed_w  = (const float*)d_in[1];
    const float* embed_b  = (const float*)d_in[2];
    const float* outc_w   = (const float*)d_in[3];
    const float* outc_b   = (const float*)d_in[4];
    const float* ln_g     = (const float*)d_in[5];
    const float* ln_b     = (const float*)d_in[6];
    const float* in_w     = (const float*)d_in[7];
    const float* conv_w   = (const float*)d_in[8];
    const float* conv_b   = (const float*)d_in[9];
    const float* xproj_w  = (const float*)d_in[10];
    const float* dtproj_w = (const float*)d_in[11];
    const float* dtproj_b = (const float*)d_in[12];
    const float* A_log    = (const float*)d_in[13];
    const float* ssm_D    = (const float*)d_in[14];
    const float* mout_w   = (const float*)d_in[15];
    const float* ffn_w1   = (const float*)d_in[16];
    const float* ffn_b1   = (const float*)d_in[17];
    const float* ffn_w2   = (const float*)d_in[18];
    const float* ffn_b2   = (const float*)d_in[19];

    float* ws    = (float*)d_ws;
    float* t     = ws;                  // (BLC,128)  1,048,576
    float* tmp2  = ws + 1048576;        // 2M: transpose-in out / dtuT
    float* ub    = ws + 3145728;        // 2M: u / dtT / ffn-mid lo
    float* zb    = ws + 5242880;        // 2M: z / ffn-mid hi
    float* ucv   = ws + 7340032;        // 2M: conv+silu out
    float* dtb   = ws + 9437184;        // 2M: y_scan
    float* bct   = ws + 11534336;       // [32][BLC]   262,144
    float* hend  = ws + 11796480;       // [NC][NCH] 1,048,576
    float* apr   = ws + 12845056;       // [NC][NCH] 1,048,576
    float* wcomb = ws + 13893632;       // 2 x 384 x 256 = 196,608  (total ~56.4 MB)
    float* out   = (float*)d_out;

    float* dtT    = ub;
    float* dtuT   = tmp2;
    float* ffnmid = ub;                 // spans ub+zb (BLC x 512)

    dim3 tb(32, 8);
    build_wcomb<<<768, 256, 0, stream>>>(xproj_w, dtproj_w, wcomb);
    transpose_kernel<<<dim3(128, 4, 2), tb, 0, stream>>>(x, tmp2, 128, 4096);
    mgemm<64, 64, 0, true, false, false, false><<<dim3(128, 2), 256, 0, stream>>>(
        tmp2, embed_w, embed_b, nullptr, nullptr, nullptr, nullptr, t, 128, 128);

    for (int i = 0; i < 2; ++i) {
        mgemm_ln<0, false, true><<<dim3(64, 4), 256, 0, stream>>>(
            t, ln_g + i * 128, ln_b + i * 128, in_w + i * 65536, nullptr, ub, zb, 512);
        conv_silu_kernel<<<2048, 256, 0, stream>>>(ub, conv_w + i * 1024, conv_b + i * 256, ucv);
        mgemm_dtbc<<<dim3(64, 3), 256, 0, stream>>>(
            ucv, wcomb + i * 98304, dtproj_b + i * 256, dtT, dtuT, bct);
        scan_phase1<<<dim3(4, NC, 2), 256, 0, stream>>>(dtT, dtuT, bct, A_log + i * 4096, hend, apr);
        scan_phase3<<<dim3(4, NC, 2), 256, 0, stream>>>(dtT, dtuT, bct, A_log + i * 4096, hend, apr, dtb);
        mgemm<64, 64, 0, false, true, true, false><<<dim3(128, 2), 256, 0, stream>>>(
            dtb, mout_w + i * 32768, nullptr, t, ucv, zb, ssm_D + i * 256, t, 128, 256);
        mgemm_ln<2, true, false><<<dim3(64, 4), 256, 0, stream>>>(
            t, ln_g + i * 128, ln_b + i * 128, ffn_w1 + i * 65536, ffn_b1 + i * 512, ffnmid, nullptr, 512);
        mgemm<64, 64, 0, true, true, false, false><<<dim3(128, 2), 256, 0, stream>>>(
            ffnmid, ffn_w2 + i * 65536, ffn_b2 + i * 128, t, nullptr, nullptr, nullptr, t, 128, 512);
    }

    // outc fused with output transpose + residual-x add
    mgemm<64, 64, 0, true, false, false, true><<<dim3(128, 2), 256, 0, stream>>>(
        t, outc_w, outc_b, x, nullptr, nullptr, nullptr, out, 128, 128);
}

// Round 11
// 486.747 us; speedup vs baseline: 1.0439x; 1.0439x over previous
//
#include <hip/hip_runtime.h>
#include <hip/hip_bf16.h>

// MambaFeatureEnhancer — B=2, C=128, L=4096, d_inner=256, N=16, R=8, 2 layers. All I/O fp32.
// All GEMMs bf16 MFMA (fp32 accum). dtproj folded into xproj (Wcomb, padded to 384 rows);
// LN fused into in_proj/ffn1; outc fused with output transpose+residual.
// Scan: NC=128 chunks, 4 n-states/lane, SEPARATE phase2 prefix (round-10 inline prefix was O(NC^2) — reverted).

#define LSEQ 4096
#define BLC  8192      // B * L
#define NC   128       // scan chunks
#define CHK  32        // chunk length
#define NCH  8192      // B * d_inner * N state channels

typedef __attribute__((ext_vector_type(4))) float f32x4;
typedef __attribute__((ext_vector_type(8))) short s16x8;

__device__ __forceinline__ unsigned short f2bu(float f) {   // fp32 -> bf16 bits, RNE
    unsigned u = __float_as_uint(f);
    return (unsigned short)((u + 0x7fffu + ((u >> 16) & 1u)) >> 16);
}
__device__ __forceinline__ float softplus_f(float v) {
    return (v > 0.f) ? v + log1pf(expf(-v)) : log1pf(expf(v));
}

// ---------------------------------------------------------------- input transpose (B,C,L)->(B,L,C)
__global__ __launch_bounds__(256) void transpose_kernel(
    const float* __restrict__ in_, float* __restrict__ out_, int R, int Cc)
{
    __shared__ float tile[32][33];
    size_t boff = (size_t)blockIdx.z * R * Cc;
    int r0 = blockIdx.y * 32, c0 = blockIdx.x * 32;
    int tx = threadIdx.x, ty = threadIdx.y;   // block (32,8)
#pragma unroll
    for (int j = 0; j < 4; ++j)
        tile[ty + j * 8][tx] = in_[boff + (size_t)(r0 + ty + j * 8) * Cc + (c0 + tx)];
    __syncthreads();
#pragma unroll
    for (int j = 0; j < 4; ++j)
        out_[boff + (size_t)(c0 + ty + j * 8) * R + (r0 + tx)] = tile[tx][ty + j * 8];
}

// ---------------------------------------------------------------- Wcomb precompute (2 x 384 x 256)
// row<256: dt-combined; 256..287: B/C rows of xproj; 288..383: zero pad.
__global__ __launch_bounds__(256) void build_wcomb(
    const float* __restrict__ xproj_w, const float* __restrict__ dtproj_w,
    float* __restrict__ wc)
{
    int i = blockIdx.x * 256 + threadIdx.x;     // 0 .. 2*384*256-1
    int layer = i / 98304;
    int rem   = i - layer * 98304;
    int row = rem >> 8, col = rem & 255;
    const float* xp = xproj_w + layer * 10240;
    float v = 0.f;
    if (row < 256) {
        const float* dw = dtproj_w + layer * 2048 + row * 8;
#pragma unroll
        for (int r = 0; r < 8; ++r) v = fmaf(dw[r], xp[r * 256 + col], v);
    } else if (row < 288) {
        v = xp[(8 + row - 256) * 256 + col];
    }
    wc[i] = v;
}

// ---------------------------------------------------------------- bf16 MFMA GEMM (generic)
// Y[m,n] = act( sum_k X[m,k]*W[n,k] + bias[n] ) (+ res[m,n]).
// EPI (K=256): X[m,k] := (X[m,k] + pu[m,k]*pD[k]) * silu(pz[m,k]) during staging.
// OUTT: write transposed out[b][n][l] = v + res[b][n][l]  (res = original x).
template<int BM, int BN, int ACT, bool BIAS, bool RES, bool EPI, bool OUTT>
__global__ __launch_bounds__(256) void mgemm(
    const float* __restrict__ X, const float* __restrict__ W,
    const float* __restrict__ bias, const float* __restrict__ res,
    const float* __restrict__ pu, const float* __restrict__ pz,
    const float* __restrict__ pD,
    float* __restrict__ Y, int N, int K)
{
    constexpr int MF = BM / 32, NF = BN / 32;
    __shared__ __align__(16) unsigned short Xs[BM * 64];
    __shared__ __align__(16) unsigned short Ws[BN * 64];
    int tid  = threadIdx.x;
    int lane = tid & 63;
    int wave = tid >> 6;
    int wm = wave >> 1, wn = wave & 1;
    int l15 = lane & 15, l4 = lane >> 4;
    int bm = blockIdx.x * BM, bn = blockIdx.y * BN;
    f32x4 acc[MF][NF] = {};
    int q  = tid & 15;
    int r0 = tid >> 4;

    for (int k0 = 0; k0 < K; k0 += 64) {
        __syncthreads();
#pragma unroll
        for (int p = 0; p < BM / 16; ++p) {
            int row = r0 + p * 16;
            size_t gi = (size_t)(bm + row) * K + k0 + q * 4;
            float4 v = *(const float4*)&X[gi];
            if (EPI) {
                float4 u4 = *(const float4*)&pu[gi];
                float4 z4 = *(const float4*)&pz[gi];
                float4 D4 = *(const float4*)&pD[k0 + q * 4];
                v.x = fmaf(u4.x, D4.x, v.x) * (z4.x / (1.f + __expf(-z4.x)));
                v.y = fmaf(u4.y, D4.y, v.y) * (z4.y / (1.f + __expf(-z4.y)));
                v.z = fmaf(u4.z, D4.z, v.z) * (z4.z / (1.f + __expf(-z4.z)));
                v.w = fmaf(u4.w, D4.w, v.w) * (z4.w / (1.f + __expf(-z4.w)));
            }
            unsigned lo = f2bu(v.x) | ((unsigned)f2bu(v.y) << 16);
            unsigned hi = f2bu(v.z) | ((unsigned)f2bu(v.w) << 16);
            int off = (row * 128 + q * 8) ^ ((row & 7) << 4);
            *(uint2*)((char*)Xs + off) = make_uint2(lo, hi);
        }
#pragma unroll
        for (int p = 0; p < BN / 16; ++p) {
            int row = r0 + p * 16;
            float4 v = *(const float4*)&W[(size_t)(bn + row) * K + k0 + q * 4];
            unsigned lo = f2bu(v.x) | ((unsigned)f2bu(v.y) << 16);
            unsigned hi = f2bu(v.z) | ((unsigned)f2bu(v.w) << 16);
            int off = (row * 128 + q * 8) ^ ((row & 7) << 4);
            *(uint2*)((char*)Ws + off) = make_uint2(lo, hi);
        }
        __syncthreads();
#pragma unroll
        for (int ks = 0; ks < 2; ++ks) {
            s16x8 a[MF], b[NF];
#pragma unroll
            for (int mf = 0; mf < MF; ++mf) {
                int row = wm * (BM / 2) + mf * 16 + l15;
                int off = (row * 128 + (ks * 32 + l4 * 8) * 2) ^ ((row & 7) << 4);
                a[mf] = *(const s16x8*)((const char*)Xs + off);
            }
#pragma unroll
            for (int nf = 0; nf < NF; ++nf) {
                int row = wn * (BN / 2) + nf * 16 + l15;
                int off = (row * 128 + (ks * 32 + l4 * 8) * 2) ^ ((row & 7) << 4);
                b[nf] = *(const s16x8*)((const char*)Ws + off);
            }
#pragma unroll
            for (int mf = 0; mf < MF; ++mf)
#pragma unroll
                for (int nf = 0; nf < NF; ++nf)
                    acc[mf][nf] = __builtin_amdgcn_mfma_f32_16x16x32_bf16(
                        a[mf], b[nf], acc[mf][nf], 0, 0, 0);
        }
    }

#pragma unroll
    for (int mf = 0; mf < MF; ++mf) {
#pragma unroll
        for (int nf = 0; nf < NF; ++nf) {
            int col   = bn + wn * (BN / 2) + nf * 16 + l15;
            int rbase = bm + wm * (BM / 2) + mf * 16 + l4 * 4;
            float bv = BIAS ? bias[col] : 0.f;
            if (OUTT) {
                int bi = rbase >> 12;
                int l  = rbase & 4095;
                size_t ob = (size_t)bi * 524288 + (size_t)col * 4096 + l;
#pragma unroll
                for (int r = 0; r < 4; ++r)
                    Y[ob + r] = acc[mf][nf][r] + bv + res[ob + r];
            } else {
#pragma unroll
                for (int r = 0; r < 4; ++r) {
                    float v = acc[mf][nf][r] + bv;
                    if (ACT == 2) v = 0.5f * v * (1.f + erff(v * 0.70710678118654752f));
                    size_t o = (size_t)(rbase + r) * N + col;
                    if (RES) v += res[o];
                    Y[o] = v;
                }
            }
        }
    }
}

// ---------------------------------------------------------------- LN-fused GEMM (BM=128, BN=128, K=128)
// X = t (BLC x 128); LN per row fused into bf16 staging. SPLIT: N=512 -> Y(0..255)/Y2(256..511).
template<int ACT, bool BIAS, bool SPLIT>
__global__ __launch_bounds__(256) void mgemm_ln(
    const float* __restrict__ X,
    const float* __restrict__ lng, const float* __restrict__ lnb,
    const float* __restrict__ W, const float* __restrict__ bias,
    float* __restrict__ Y, float* __restrict__ Y2, int N)
{
    __shared__ __align__(16) unsigned short Xs[128 * 128];   // 32 KB
    __shared__ __align__(16) unsigned short Ws[128 * 64];    // 16 KB
    int tid  = threadIdx.x;
    int lane = tid & 63;
    int wave = tid >> 6;
    int wm = wave >> 1, wn = wave & 1;
    int l15 = lane & 15, l4 = lane >> 4;
    int bm = blockIdx.x * 128, bn = blockIdx.y * 128;

    // ---- LN + quantize X tile (128 rows x 128 cols)
    int rsub = lane >> 4;   // 0..3
    int cg   = lane & 15;   // 0..15, 8 cols each
    float4 ga = *(const float4*)&lng[cg * 8], gb = *(const float4*)&lng[cg * 8 + 4];
    float4 ba = *(const float4*)&lnb[cg * 8], bb2 = *(const float4*)&lnb[cg * 8 + 4];
#pragma unroll 2
    for (int it = 0; it < 8; ++it) {
        int row = wave * 32 + it * 4 + rsub;
        const float* xr = X + (size_t)(bm + row) * 128 + cg * 8;
        float4 xa = *(const float4*)xr;
        float4 xb = *(const float4*)(xr + 4);
        float s = xa.x + xa.y + xa.z + xa.w + xb.x + xb.y + xb.z + xb.w;
        float q = xa.x*xa.x + xa.y*xa.y + xa.z*xa.z + xa.w*xa.w
                + xb.x*xb.x + xb.y*xb.y + xb.z*xb.z + xb.w*xb.w;
        s += __shfl_xor(s, 1, 16); q += __shfl_xor(q, 1, 16);
        s += __shfl_xor(s, 2, 16); q += __shfl_xor(q, 2, 16);
        s += __shfl_xor(s, 4, 16); q += __shfl_xor(q, 4, 16);
        s += __shfl_xor(s, 8, 16); q += __shfl_xor(q, 8, 16);
        float mean = s * 0.0078125f;
        float var  = fmaf(-mean, mean, q * 0.0078125f);
        float rstd = rsqrtf(var + 1e-5f);
        float o0 = fmaf((xa.x - mean) * rstd, ga.x, ba.x);
        float o1 = fmaf((xa.y - mean) * rstd, ga.y, ba.y);
        float o2 = fmaf((xa.z - mean) * rstd, ga.z, ba.z);
        float o3 = fmaf((xa.w - mean) * rstd, ga.w, ba.w);
        float o4 = fmaf((xb.x - mean) * rstd, gb.x, bb2.x);
        float o5 = fmaf((xb.y - mean) * rstd, gb.y, bb2.y);
        float o6 = fmaf((xb.z - mean) * rstd, gb.z, bb2.z);
        float o7 = fmaf((xb.w - mean) * rstd, gb.w, bb2.w);
        uint4 wv;
        wv.x = f2bu(o0) | ((unsigned)f2bu(o1) << 16);
        wv.y = f2bu(o2) | ((unsigned)f2bu(o3) << 16);
        wv.z = f2bu(o4) | ((unsigned)f2bu(o5) << 16);
        wv.w = f2bu(o6) | ((unsigned)f2bu(o7) << 16);
        int off = (row * 256 + cg * 16) ^ ((row & 7) << 4);
        *(uint4*)((char*)Xs + off) = wv;
    }

    f32x4 acc[4][4] = {};
    int q4 = tid & 15, r0 = tid >> 4;
    for (int k0 = 0; k0 < 128; k0 += 64) {
#pragma unroll
        for (int p = 0; p < 8; ++p) {
            int row = r0 + p * 16;
            float4 v = *(const float4*)&W[(size_t)(bn + row) * 128 + k0 + q4 * 4];
            unsigned lo = f2bu(v.x) | ((unsigned)f2bu(v.y) << 16);
            unsigned hi = f2bu(v.z) | ((unsigned)f2bu(v.w) << 16);
            int off = (row * 128 + q4 * 8) ^ ((row & 7) << 4);
            *(uint2*)((char*)Ws + off) = make_uint2(lo, hi);
        }
        __syncthreads();
#pragma unroll
        for (int ks = 0; ks < 2; ++ks) {
            s16x8 a[4], b[4];
#pragma unroll
            for (int mf = 0; mf < 4; ++mf) {
                int row = wm * 64 + mf * 16 + l15;
                int off = (row * 256 + (k0 + ks * 32 + l4 * 8) * 2) ^ ((row & 7) << 4);
                a[mf] = *(const s16x8*)((const char*)Xs + off);
            }
#pragma unroll
            for (int nf = 0; nf < 4; ++nf) {
                int row = wn * 64 + nf * 16 + l15;
                int off = (row * 128 + (ks * 32 + l4 * 8) * 2) ^ ((row & 7) << 4);
                b[nf] = *(const s16x8*)((const char*)Ws + off);
            }
#pragma unroll
            for (int mf = 0; mf < 4; ++mf)
#pragma unroll
                for (int nf = 0; nf < 4; ++nf)
                    acc[mf][nf] = __builtin_amdgcn_mfma_f32_16x16x32_bf16(
                        a[mf], b[nf], acc[mf][nf], 0, 0, 0);
        }
        __syncthreads();
    }

#pragma unroll
    for (int mf = 0; mf < 4; ++mf) {
#pragma unroll
        for (int nf = 0; nf < 4; ++nf) {
            int col   = bn + wn * 64 + nf * 16 + l15;
            int rbase = bm + wm * 64 + mf * 16 + l4 * 4;
            float bv = BIAS ? bias[col] : 0.f;
#pragma unroll
            for (int r = 0; r < 4; ++r) {
                float v = acc[mf][nf][r] + bv;
                if (ACT == 2) v = 0.5f * v * (1.f + erff(v * 0.70710678118654752f));
                if (SPLIT) {
                    if (col < 256) Y [(size_t)(rbase + r) * 256 + col]       = v;
                    else           Y2[(size_t)(rbase + r) * 256 + col - 256] = v;
                } else {
                    Y[(size_t)(rbase + r) * N + col] = v;
                }
            }
        }
    }
}

// ---------------------------------------------------------------- dt+B/C GEMM (BM=128, BN=128, K=256)
// Blocks bn<2: dt = softplus(acc+bias) -> dtT[d][row], dtuT = dt*u.
// Block bn==2: cols 0..31 -> bct[n][row] (B rows 0..15, C rows 16..31).
__global__ __launch_bounds__(256) void mgemm_dtbc(
    const float* __restrict__ Xu, const float* __restrict__ W,
    const float* __restrict__ bias,
    float* __restrict__ dtT, float* __restrict__ dtuT, float* __restrict__ bct)
{
    __shared__ __align__(16) unsigned short Xs[128 * 64];
    __shared__ __align__(16) unsigned short Ws[128 * 64];
    int tid  = threadIdx.x;
    int lane = tid & 63;
    int wave = tid >> 6;
    int wm = wave >> 1, wn = wave & 1;
    int l15 = lane & 15, l4 = lane >> 4;
    int bm = blockIdx.x * 128, bn = blockIdx.y * 128;
    f32x4 acc[4][4] = {};
    int q  = tid & 15;
    int r0 = tid >> 4;

    for (int k0 = 0; k0 < 256; k0 += 64) {
        __syncthreads();
#pragma unroll
        for (int p = 0; p < 8; ++p) {
            int row = r0 + p * 16;
            float4 v = *(const float4*)&Xu[(size_t)(bm + row) * 256 + k0 + q * 4];
            unsigned lo = f2bu(v.x) | ((unsigned)f2bu(v.y) << 16);
            unsigned hi = f2bu(v.z) | ((unsigned)f2bu(v.w) << 16);
            int off = (row * 128 + q * 8) ^ ((row & 7) << 4);
            *(uint2*)((char*)Xs + off) = make_uint2(lo, hi);
        }
#pragma unroll
        for (int p = 0; p < 8; ++p) {
            int row = r0 + p * 16;
            float4 v = *(const float4*)&W[(size_t)(bn + row) * 256 + k0 + q * 4];
            unsigned lo = f2bu(v.x) | ((unsigned)f2bu(v.y) << 16);
            unsigned hi = f2bu(v.z) | ((unsigned)f2bu(v.w) << 16);
            int off = (row * 128 + q * 8) ^ ((row & 7) << 4);
            *(uint2*)((char*)Ws + off) = make_uint2(lo, hi);
        }
        __syncthreads();
#pragma unroll
        for (int ks = 0; ks < 2; ++ks) {
            s16x8 a[4], b[4];
#pragma unroll
            for (int mf = 0; mf < 4; ++mf) {
                int row = wm * 64 + mf * 16 + l15;
                int off = (row * 128 + (ks * 32 + l4 * 8) * 2) ^ ((row & 7) << 4);
                a[mf] = *(const s16x8*)((const char*)Xs + off);
            }
#pragma unroll
            for (int nf = 0; nf < 4; ++nf) {
                int row = wn * 64 + nf * 16 + l15;
                int off = (row * 128 + (ks * 32 + l4 * 8) * 2) ^ ((row & 7) << 4);
                b[nf] = *(const s16x8*)((const char*)Ws + off);
            }
#pragma unroll
            for (int mf = 0; mf < 4; ++mf)
#pragma unroll
                for (int nf = 0; nf < 4; ++nf)
                    acc[mf][nf] = __builtin_amdgcn_mfma_f32_16x16x32_bf16(
                        a[mf], b[nf], acc[mf][nf], 0, 0, 0);
        }
    }

    if (blockIdx.y < 2) {
#pragma unroll
        for (int mf = 0; mf < 4; ++mf) {
#pragma unroll
            for (int nf = 0; nf < 4; ++nf) {
                int col   = bn + wn * 64 + nf * 16 + l15;
                int rbase = bm + wm * 64 + mf * 16 + l4 * 4;
                float bv = bias[col];
                float4 uu;
                uu.x = Xu[(size_t)(rbase + 0) * 256 + col];
                uu.y = Xu[(size_t)(rbase + 1) * 256 + col];
                uu.z = Xu[(size_t)(rbase + 2) * 256 + col];
                uu.w = Xu[(size_t)(rbase + 3) * 256 + col];
                float v0 = softplus_f(acc[mf][nf][0] + bv);
                float v1 = softplus_f(acc[mf][nf][1] + bv);
                float v2 = softplus_f(acc[mf][nf][2] + bv);
                float v3 = softplus_f(acc[mf][nf][3] + bv);
                *(float4*)&dtT [(size_t)col * BLC + rbase] = make_float4(v0, v1, v2, v3);
                *(float4*)&dtuT[(size_t)col * BLC + rbase] =
                    make_float4(v0 * uu.x, v1 * uu.y, v2 * uu.z, v3 * uu.w);
            }
        }
    } else {
#pragma unroll
        for (int mf = 0; mf < 4; ++mf) {
#pragma unroll
            for (int nf = 0; nf < 4; ++nf) {
                int col16 = wn * 64 + nf * 16 + l15;     // valid < 32
                int rbase = bm + wm * 64 + mf * 16 + l4 * 4;
                if (col16 < 32) {
                    *(float4*)&bct[(size_t)col16 * BLC + rbase] =
                        make_float4(acc[mf][nf][0], acc[mf][nf][1],
                                    acc[mf][nf][2], acc[mf][nf][3]);
                }
            }
        }
    }
}

// ---------------------------------------------------------------- conv1d (depthwise causal k=4) + silu
__global__ __launch_bounds__(256) void conv_silu_kernel(
    const float* __restrict__ u, const float* __restrict__ cw,
    const float* __restrict__ cb, float* __restrict__ out)
{
    int i   = blockIdx.x * 256 + threadIdx.x;   // BLC * 64
    int dq  = (i & 63) << 2;
    int row = i >> 6;
    int l   = row & (LSEQ - 1);
    float4 a = *(const float4*)&cb[dq];
    float w[4][4];
#pragma unroll
    for (int e = 0; e < 4; ++e) {
        float4 we = *(const float4*)&cw[(dq + e) * 4];
        w[e][0] = we.x; w[e][1] = we.y; w[e][2] = we.z; w[e][3] = we.w;
    }
#pragma unroll
    for (int j = 0; j < 4; ++j) {
        if (l >= 3 - j) {
            const float4 v = *(const float4*)&u[(size_t)(row - 3 + j) * 256 + dq];
            a.x = fmaf(v.x, w[0][j], a.x);
            a.y = fmaf(v.y, w[1][j], a.y);
            a.z = fmaf(v.z, w[2][j], a.z);
            a.w = fmaf(v.w, w[3][j], a.w);
        }
    }
    float4 o;
    o.x = a.x / (1.f + __expf(-a.x));
    o.y = a.y / (1.f + __expf(-a.y));
    o.z = a.z / (1.f + __expf(-a.z));
    o.w = a.w / (1.f + __expf(-a.w));
    *(float4*)&out[(size_t)row * 256 + dq] = o;
}

// ---------------------------------------------------------------- chunked selective scan
// Lane owns 4 n-states of one d: g = tid&3, dloc = tid>>2. grid (4, NC, B) = 1024 blocks.
__global__ __launch_bounds__(256) void scan_phase1(
    const float* __restrict__ dtT, const float* __restrict__ dtuT,
    const float* __restrict__ bct, const float* __restrict__ A_log,
    float* __restrict__ hend, float* __restrict__ aprod)
{
    int g    = threadIdx.x & 3;
    int dloc = threadIdx.x >> 2;
    int d    = blockIdx.x * 64 + dloc;
    int c    = blockIdx.y;
    int b    = blockIdx.z;
    float4 al = *(const float4*)&A_log[d * 16 + g * 4];
    float A0 = -__expf(al.x), A1 = -__expf(al.y), A2 = -__expf(al.z), A3 = -__expf(al.w);
    int base   = d * BLC + b * LSEQ + c * CHK;
    int btbase = b * LSEQ + c * CHK;
    const float* B0p = bct + (size_t)(g * 4 + 0) * BLC + btbase;
    const float* B1p = B0p + BLC;
    const float* B2p = B1p + BLC;
    const float* B3p = B2p + BLC;
    float h0 = 0.f, h1 = 0.f, h2 = 0.f, h3 = 0.f;
    float p0 = 1.f, p1 = 1.f, p2 = 1.f, p3 = 1.f;
#pragma unroll 2
    for (int t4 = 0; t4 < CHK; t4 += 4) {
        float4 dt4 = *(const float4*)&dtT [base + t4];
        float4 du4 = *(const float4*)&dtuT[base + t4];
        float4 B0 = *(const float4*)(B0p + t4);
        float4 B1 = *(const float4*)(B1p + t4);
        float4 B2 = *(const float4*)(B2p + t4);
        float4 B3 = *(const float4*)(B3p + t4);
        float dts[4] = {dt4.x, dt4.y, dt4.z, dt4.w};
        float dus[4] = {du4.x, du4.y, du4.z, du4.w};
        float b0[4] = {B0.x, B0.y, B0.z, B0.w};
        float b1[4] = {B1.x, B1.y, B1.z, B1.w};
        float b2[4] = {B2.x, B2.y, B2.z, B2.w};
        float b3[4] = {B3.x, B3.y, B3.z, B3.w};
#pragma unroll
        for (int j = 0; j < 4; ++j) {
            float a0 = __expf(dts[j] * A0), a1 = __expf(dts[j] * A1);
            float a2 = __expf(dts[j] * A2), a3 = __expf(dts[j] * A3);
            h0 = fmaf(a0, h0, dus[j] * b0[j]); p0 *= a0;
            h1 = fmaf(a1, h1, dus[j] * b1[j]); p1 *= a1;
            h2 = fmaf(a2, h2, dus[j] * b2[j]); p2 *= a2;
            h3 = fmaf(a3, h3, dus[j] * b3[j]); p3 *= a3;
        }
    }
    int ch = (b * 256 + d) * 16 + g * 4;
    *(float4*)&hend [c * NCH + ch] = make_float4(h0, h1, h2, h3);
    *(float4*)&aprod[c * NCH + ch] = make_float4(p0, p1, p2, p3);
}

// Serial prefix over chunks; h0 written in place of aprod. Coalesced [c][ch] layout. O(NC) total.
__global__ __launch_bounds__(256) void scan_phase2(
    const float* __restrict__ hend, float* __restrict__ apr_h0)
{
    int ch = blockIdx.x * 256 + threadIdx.x;   // NCH
    float h = 0.f;
#pragma unroll 4
    for (int c = 0; c < NC; ++c) {
        float ap = apr_h0[c * NCH + ch];
        float he = hend[c * NCH + ch];
        apr_h0[c * NCH + ch] = h;
        h = fmaf(ap, h, he);
    }
}

// Phase 3: read h0 from apr, recompute chunk + C-dot + write y[row][d].
__global__ __launch_bounds__(256) void scan_phase3(
    const float* __restrict__ dtT, const float* __restrict__ dtuT,
    const float* __restrict__ bct, const float* __restrict__ A_log,
    const float* __restrict__ h0b, float* __restrict__ y)
{
    int g    = threadIdx.x & 3;
    int dloc = threadIdx.x >> 2;
    int d    = blockIdx.x * 64 + dloc;
    int c    = blockIdx.y;
    int b    = blockIdx.z;
    float4 al = *(const float4*)&A_log[d * 16 + g * 4];
    float A0 = -__expf(al.x), A1 = -__expf(al.y), A2 = -__expf(al.z), A3 = -__expf(al.w);
    int ch = (b * 256 + d) * 16 + g * 4;
    float4 hv = *(const float4*)&h0b[c * NCH + ch];
    float h0 = hv.x, h1 = hv.y, h2 = hv.z, h3 = hv.w;
    int base = d * BLC + b * LSEQ + c * CHK;
    int row0 = b * LSEQ + c * CHK;
    const float* B0p = bct + (size_t)(g * 4 + 0) * BLC + row0;
    const float* B1p = B0p + BLC;
    const float* B2p = B1p + BLC;
    const float* B3p = B2p + BLC;
    const float* C0p = bct + (size_t)(16 + g * 4) * BLC + row0;
    const float* C1p = C0p + BLC;
    const float* C2p = C1p + BLC;
    const float* C3p = C2p + BLC;
#pragma unroll 2
    for (int t4 = 0; t4 < CHK; t4 += 4) {
        float4 dt4 = *(const float4*)&dtT [base + t4];
        float4 du4 = *(const float4*)&dtuT[base + t4];
        float4 B0 = *(const float4*)(B0p + t4);
        float4 B1 = *(const float4*)(B1p + t4);
        float4 B2 = *(const float4*)(B2p + t4);
        float4 B3 = *(const float4*)(B3p + t4);
        float4 C0 = *(const float4*)(C0p + t4);
        float4 C1 = *(const float4*)(C1p + t4);
        float4 C2 = *(const float4*)(C2p + t4);
        float4 C3 = *(const float4*)(C3p + t4);
        float dts[4] = {dt4.x, dt4.y, dt4.z, dt4.w};
        float dus[4] = {du4.x, du4.y, du4.z, du4.w};
        float b0[4] = {B0.x, B0.y, B0.z, B0.w};
        float b1[4] = {B1.x, B1.y, B1.z, B1.w};
        float b2[4] = {B2.x, B2.y, B2.z, B2.w};
        float b3[4] = {B3.x, B3.y, B3.z, B3.w};
        float c0[4] = {C0.x, C0.y, C0.z, C0.w};
        float c1[4] = {C1.x, C1.y, C1.z, C1.w};
        float c2[4] = {C2.x, C2.y, C2.z, C2.w};
        float c3[4] = {C3.x, C3.y, C3.z, C3.w};
#pragma unroll
        for (int j = 0; j < 4; ++j) {
            float a0 = __expf(dts[j] * A0), a1 = __expf(dts[j] * A1);
            float a2 = __expf(dts[j] * A2), a3 = __expf(dts[j] * A3);
            h0 = fmaf(a0, h0, dus[j] * b0[j]);
            h1 = fmaf(a1, h1, dus[j] * b1[j]);
            h2 = fmaf(a2, h2, dus[j] * b2[j]);
            h3 = fmaf(a3, h3, dus[j] * b3[j]);
            float p = h0 * c0[j];
            p = fmaf(h1, c1[j], p);
            p = fmaf(h2, c2[j], p);
            p = fmaf(h3, c3[j], p);
            p += __shfl_xor(p, 1);
            p += __shfl_xor(p, 2);
            if (g == 0) y[(size_t)(row0 + t4 + j) * 256 + d] = p;
        }
    }
}

// ---------------------------------------------------------------- launch
extern "C" void kernel_launch(void* const* d_in, const int* in_sizes, int n_in,
                              void* d_out, int out_size, void* d_ws, size_t ws_size,
                              hipStream_t stream)
{
    const float* x        = (const float*)d_in[0];
    const float* embed_w  = (const float*)d_in[1];
    const float* embed_b  = (const float*)d_in[2];
    const float* outc_w   = (const float*)d_in[3];
    const float* outc_b   = (const float*)d_in[4];
    const float* ln_g     = (const float*)d_in[5];
    const float* ln_b     = (const float*)d_in[6];
    const float* in_w     = (const float*)d_in[7];
    const float* conv_w   = (const float*)d_in[8];
    const float* conv_b   = (const float*)d_in[9];
    const float* xproj_w  = (const float*)d_in[10];
    const float* dtproj_w = (const float*)d_in[11];
    const float* dtproj_b = (const float*)d_in[12];
    const float* A_log    = (const float*)d_in[13];
    const float* ssm_D    = (const float*)d_in[14];
    const float* mout_w   = (const float*)d_in[15];
    const float* ffn_w1   = (const float*)d_in[16];
    const float* ffn_b1   = (const float*)d_in[17];
    const float* ffn_w2   = (const float*)d_in[18];
    const float* ffn_b2   = (const float*)d_in[19];

    float* ws    = (float*)d_ws;
    float* t     = ws;                  // (BLC,128)  1,048,576
    float* tmp2  = ws + 1048576;        // 2M: transpose-in out / dtuT
    float* ub    = ws + 3145728;        // 2M: u / dtT / ffn-mid lo
    float* zb    = ws + 5242880;        // 2M: z / ffn-mid hi
    float* ucv   = ws + 7340032;        // 2M: conv+silu out
    float* dtb   = ws + 9437184;        // 2M: y_scan
    float* bct   = ws + 11534336;       // [32][BLC]   262,144
    float* hend  = ws + 11796480;       // [NC][NCH] 1,048,576
    float* apr   = ws + 12845056;       // [NC][NCH] 1,048,576 -> h0
    float* wcomb = ws + 13893632;       // 2 x 384 x 256 = 196,608  (total ~56.4 MB)
    float* out   = (float*)d_out;

    float* dtT    = ub;
    float* dtuT   = tmp2;
    float* ffnmid = ub;                 // spans ub+zb (BLC x 512)

    dim3 tb(32, 8);
    build_wcomb<<<768, 256, 0, stream>>>(xproj_w, dtproj_w, wcomb);
    transpose_kernel<<<dim3(128, 4, 2), tb, 0, stream>>>(x, tmp2, 128, 4096);
    mgemm<64, 64, 0, true, false, false, false><<<dim3(128, 2), 256, 0, stream>>>(
        tmp2, embed_w, embed_b, nullptr, nullptr, nullptr, nullptr, t, 128, 128);

    for (int i = 0; i < 2; ++i) {
        mgemm_ln<0, false, true><<<dim3(64, 4), 256, 0, stream>>>(
            t, ln_g + i * 128, ln_b + i * 128, in_w + i * 65536, nullptr, ub, zb, 512);
        conv_silu_kernel<<<2048, 256, 0, stream>>>(ub, conv_w + i * 1024, conv_b + i * 256, ucv);
        mgemm_dtbc<<<dim3(64, 3), 256, 0, stream>>>(
            ucv, wcomb + i * 98304, dtproj_b + i * 256, dtT, dtuT, bct);
        scan_phase1<<<dim3(4, NC, 2), 256, 0, stream>>>(dtT, dtuT, bct, A_log + i * 4096, hend, apr);
        scan_phase2<<<32, 256, 0, stream>>>(hend, apr);
        scan_phase3<<<dim3(4, NC, 2), 256, 0, stream>>>(dtT, dtuT, bct, A_log + i * 4096, apr, dtb);
        mgemm<64, 64, 0, false, true, true, false><<<dim3(128, 2), 256, 0, stream>>>(
            dtb, mout_w + i * 32768, nullptr, t, ucv, zb, ssm_D + i * 256, t, 128, 256);
        mgemm_ln<2, true, false><<<dim3(64, 4), 256, 0, stream>>>(
            t, ln_g + i * 128, ln_b + i * 128, ffn_w1 + i * 65536, ffn_b1 + i * 512, ffnmid, nullptr, 512);
        mgemm<64, 64, 0, true, true, false, false><<<dim3(128, 2), 256, 0, stream>>>(
            ffnmid, ffn_w2 + i * 65536, ffn_b2 + i * 128, t, nullptr, nullptr, nullptr, t, 128, 512);
    }

    // outc fused with output transpose + residual-x add
    mgemm<64, 64, 0, true, false, false, true><<<dim3(128, 2), 256, 0, stream>>>(
        t, outc_w, outc_b, x, nullptr, nullptr, nullptr, out, 128, 128);
}

// Round 12
// 470.804 us; speedup vs baseline: 1.0793x; 1.0339x over previous
//
#include <hip/hip_runtime.h>
#include <hip/hip_bf16.h>

// MambaFeatureEnhancer — B=2, C=128, L=4096, d_inner=256, N=16, R=8, 2 layers. All I/O fp32.
// All GEMMs bf16 MFMA (fp32 accum). dtproj folded into xproj (Wcomb); LN fused into
// in_proj/ffn1; outc fused with output transpose+residual. Scan: NC=128, separate phase2.
// R11 lesson: grids must exceed 256 CUs — dtbc BM=BN=64 (640 blocks), mgemm_ln BN=64 (512).

#define LSEQ 4096
#define BLC  8192      // B * L
#define NC   128       // scan chunks
#define CHK  32        // chunk length
#define NCH  8192      // B * d_inner * N state channels

typedef __attribute__((ext_vector_type(4))) float f32x4;
typedef __attribute__((ext_vector_type(8))) short s16x8;

__device__ __forceinline__ unsigned short f2bu(float f) {   // fp32 -> bf16 bits, RNE
    unsigned u = __float_as_uint(f);
    return (unsigned short)((u + 0x7fffu + ((u >> 16) & 1u)) >> 16);
}
__device__ __forceinline__ float softplus_f(float v) {
    return (v > 0.f) ? v + log1pf(expf(-v)) : log1pf(expf(v));
}

// ---------------------------------------------------------------- input transpose (B,C,L)->(B,L,C)
__global__ __launch_bounds__(256) void transpose_kernel(
    const float* __restrict__ in_, float* __restrict__ out_, int R, int Cc)
{
    __shared__ float tile[32][33];
    size_t boff = (size_t)blockIdx.z * R * Cc;
    int r0 = blockIdx.y * 32, c0 = blockIdx.x * 32;
    int tx = threadIdx.x, ty = threadIdx.y;   // block (32,8)
#pragma unroll
    for (int j = 0; j < 4; ++j)
        tile[ty + j * 8][tx] = in_[boff + (size_t)(r0 + ty + j * 8) * Cc + (c0 + tx)];
    __syncthreads();
#pragma unroll
    for (int j = 0; j < 4; ++j)
        out_[boff + (size_t)(c0 + ty + j * 8) * R + (r0 + tx)] = tile[tx][ty + j * 8];
}

// ---------------------------------------------------------------- Wcomb precompute (2 x 384 x 256)
// row<256: dt-combined; 256..287: B/C rows of xproj; 288..383: zero pad.
__global__ __launch_bounds__(256) void build_wcomb(
    const float* __restrict__ xproj_w, const float* __restrict__ dtproj_w,
    float* __restrict__ wc)
{
    int i = blockIdx.x * 256 + threadIdx.x;     // 0 .. 2*384*256-1
    int layer = i / 98304;
    int rem   = i - layer * 98304;
    int row = rem >> 8, col = rem & 255;
    const float* xp = xproj_w + layer * 10240;
    float v = 0.f;
    if (row < 256) {
        const float* dw = dtproj_w + layer * 2048 + row * 8;
#pragma unroll
        for (int r = 0; r < 8; ++r) v = fmaf(dw[r], xp[r * 256 + col], v);
    } else if (row < 288) {
        v = xp[(8 + row - 256) * 256 + col];
    }
    wc[i] = v;
}

// ---------------------------------------------------------------- bf16 MFMA GEMM (generic)
// Y[m,n] = act( sum_k X[m,k]*W[n,k] + bias[n] ) (+ res[m,n]).
// EPI (K=256): X[m,k] := (X[m,k] + pu[m,k]*pD[k]) * silu(pz[m,k]) during staging.
// OUTT: write transposed out[b][n][l] = v + res[b][n][l]  (res = original x).
template<int BM, int BN, int ACT, bool BIAS, bool RES, bool EPI, bool OUTT>
__global__ __launch_bounds__(256) void mgemm(
    const float* __restrict__ X, const float* __restrict__ W,
    const float* __restrict__ bias, const float* __restrict__ res,
    const float* __restrict__ pu, const float* __restrict__ pz,
    const float* __restrict__ pD,
    float* __restrict__ Y, int N, int K)
{
    constexpr int MF = BM / 32, NF = BN / 32;
    __shared__ __align__(16) unsigned short Xs[BM * 64];
    __shared__ __align__(16) unsigned short Ws[BN * 64];
    int tid  = threadIdx.x;
    int lane = tid & 63;
    int wave = tid >> 6;
    int wm = wave >> 1, wn = wave & 1;
    int l15 = lane & 15, l4 = lane >> 4;
    int bm = blockIdx.x * BM, bn = blockIdx.y * BN;
    f32x4 acc[MF][NF] = {};
    int q  = tid & 15;
    int r0 = tid >> 4;

    for (int k0 = 0; k0 < K; k0 += 64) {
        __syncthreads();
#pragma unroll
        for (int p = 0; p < BM / 16; ++p) {
            int row = r0 + p * 16;
            size_t gi = (size_t)(bm + row) * K + k0 + q * 4;
            float4 v = *(const float4*)&X[gi];
            if (EPI) {
                float4 u4 = *(const float4*)&pu[gi];
                float4 z4 = *(const float4*)&pz[gi];
                float4 D4 = *(const float4*)&pD[k0 + q * 4];
                v.x = fmaf(u4.x, D4.x, v.x) * (z4.x / (1.f + __expf(-z4.x)));
                v.y = fmaf(u4.y, D4.y, v.y) * (z4.y / (1.f + __expf(-z4.y)));
                v.z = fmaf(u4.z, D4.z, v.z) * (z4.z / (1.f + __expf(-z4.z)));
                v.w = fmaf(u4.w, D4.w, v.w) * (z4.w / (1.f + __expf(-z4.w)));
            }
            unsigned lo = f2bu(v.x) | ((unsigned)f2bu(v.y) << 16);
            unsigned hi = f2bu(v.z) | ((unsigned)f2bu(v.w) << 16);
            int off = (row * 128 + q * 8) ^ ((row & 7) << 4);
            *(uint2*)((char*)Xs + off) = make_uint2(lo, hi);
        }
#pragma unroll
        for (int p = 0; p < BN / 16; ++p) {
            int row = r0 + p * 16;
            float4 v = *(const float4*)&W[(size_t)(bn + row) * K + k0 + q * 4];
            unsigned lo = f2bu(v.x) | ((unsigned)f2bu(v.y) << 16);
            unsigned hi = f2bu(v.z) | ((unsigned)f2bu(v.w) << 16);
            int off = (row * 128 + q * 8) ^ ((row & 7) << 4);
            *(uint2*)((char*)Ws + off) = make_uint2(lo, hi);
        }
        __syncthreads();
#pragma unroll
        for (int ks = 0; ks < 2; ++ks) {
            s16x8 a[MF], b[NF];
#pragma unroll
            for (int mf = 0; mf < MF; ++mf) {
                int row = wm * (BM / 2) + mf * 16 + l15;
                int off = (row * 128 + (ks * 32 + l4 * 8) * 2) ^ ((row & 7) << 4);
                a[mf] = *(const s16x8*)((const char*)Xs + off);
            }
#pragma unroll
            for (int nf = 0; nf < NF; ++nf) {
                int row = wn * (BN / 2) + nf * 16 + l15;
                int off = (row * 128 + (ks * 32 + l4 * 8) * 2) ^ ((row & 7) << 4);
                b[nf] = *(const s16x8*)((const char*)Ws + off);
            }
#pragma unroll
            for (int mf = 0; mf < MF; ++mf)
#pragma unroll
                for (int nf = 0; nf < NF; ++nf)
                    acc[mf][nf] = __builtin_amdgcn_mfma_f32_16x16x32_bf16(
                        a[mf], b[nf], acc[mf][nf], 0, 0, 0);
        }
    }

#pragma unroll
    for (int mf = 0; mf < MF; ++mf) {
#pragma unroll
        for (int nf = 0; nf < NF; ++nf) {
            int col   = bn + wn * (BN / 2) + nf * 16 + l15;
            int rbase = bm + wm * (BM / 2) + mf * 16 + l4 * 4;
            float bv = BIAS ? bias[col] : 0.f;
            if (OUTT) {
                int bi = rbase >> 12;
                int l  = rbase & 4095;
                size_t ob = (size_t)bi * 524288 + (size_t)col * 4096 + l;
#pragma unroll
                for (int r = 0; r < 4; ++r)
                    Y[ob + r] = acc[mf][nf][r] + bv + res[ob + r];
            } else {
#pragma unroll
                for (int r = 0; r < 4; ++r) {
                    float v = acc[mf][nf][r] + bv;
                    if (ACT == 2) v = 0.5f * v * (1.f + erff(v * 0.70710678118654752f));
                    size_t o = (size_t)(rbase + r) * N + col;
                    if (RES) v += res[o];
                    Y[o] = v;
                }
            }
        }
    }
}

// ---------------------------------------------------------------- LN-fused GEMM (BM=128, BN=64, K=128)
// X = t (BLC x 128); LN per row fused into bf16 staging. SPLIT: N=512 -> Y(0..255)/Y2(256..511).
// grid (64, N/64) = 512 blocks.
template<int ACT, bool BIAS, bool SPLIT>
__global__ __launch_bounds__(256) void mgemm_ln(
    const float* __restrict__ X,
    const float* __restrict__ lng, const float* __restrict__ lnb,
    const float* __restrict__ W, const float* __restrict__ bias,
    float* __restrict__ Y, float* __restrict__ Y2, int N)
{
    __shared__ __align__(16) unsigned short Xs[128 * 128];   // 32 KB
    __shared__ __align__(16) unsigned short Ws[64 * 64];     // 8 KB
    int tid  = threadIdx.x;
    int lane = tid & 63;
    int wave = tid >> 6;
    int wm = wave >> 1, wn = wave & 1;
    int l15 = lane & 15, l4 = lane >> 4;
    int bm = blockIdx.x * 128, bn = blockIdx.y * 64;

    // ---- LN + quantize X tile (128 rows x 128 cols)
    int rsub = lane >> 4;   // 0..3
    int cg   = lane & 15;   // 0..15, 8 cols each
    float4 ga = *(const float4*)&lng[cg * 8], gb = *(const float4*)&lng[cg * 8 + 4];
    float4 ba = *(const float4*)&lnb[cg * 8], bb2 = *(const float4*)&lnb[cg * 8 + 4];
#pragma unroll 2
    for (int it = 0; it < 8; ++it) {
        int row = wave * 32 + it * 4 + rsub;
        const float* xr = X + (size_t)(bm + row) * 128 + cg * 8;
        float4 xa = *(const float4*)xr;
        float4 xb = *(const float4*)(xr + 4);
        float s = xa.x + xa.y + xa.z + xa.w + xb.x + xb.y + xb.z + xb.w;
        float q = xa.x*xa.x + xa.y*xa.y + xa.z*xa.z + xa.w*xa.w
                + xb.x*xb.x + xb.y*xb.y + xb.z*xb.z + xb.w*xb.w;
        s += __shfl_xor(s, 1, 16); q += __shfl_xor(q, 1, 16);
        s += __shfl_xor(s, 2, 16); q += __shfl_xor(q, 2, 16);
        s += __shfl_xor(s, 4, 16); q += __shfl_xor(q, 4, 16);
        s += __shfl_xor(s, 8, 16); q += __shfl_xor(q, 8, 16);
        float mean = s * 0.0078125f;
        float var  = fmaf(-mean, mean, q * 0.0078125f);
        float rstd = rsqrtf(var + 1e-5f);
        float o0 = fmaf((xa.x - mean) * rstd, ga.x, ba.x);
        float o1 = fmaf((xa.y - mean) * rstd, ga.y, ba.y);
        float o2 = fmaf((xa.z - mean) * rstd, ga.z, ba.z);
        float o3 = fmaf((xa.w - mean) * rstd, ga.w, ba.w);
        float o4 = fmaf((xb.x - mean) * rstd, gb.x, bb2.x);
        float o5 = fmaf((xb.y - mean) * rstd, gb.y, bb2.y);
        float o6 = fmaf((xb.z - mean) * rstd, gb.z, bb2.z);
        float o7 = fmaf((xb.w - mean) * rstd, gb.w, bb2.w);
        uint4 wv;
        wv.x = f2bu(o0) | ((unsigned)f2bu(o1) << 16);
        wv.y = f2bu(o2) | ((unsigned)f2bu(o3) << 16);
        wv.z = f2bu(o4) | ((unsigned)f2bu(o5) << 16);
        wv.w = f2bu(o6) | ((unsigned)f2bu(o7) << 16);
        int off = (row * 256 + cg * 16) ^ ((row & 7) << 4);
        *(uint4*)((char*)Xs + off) = wv;
    }

    f32x4 acc[4][2] = {};
    int q4 = tid & 15, r0 = tid >> 4;
    for (int k0 = 0; k0 < 128; k0 += 64) {
#pragma unroll
        for (int p = 0; p < 4; ++p) {
            int row = r0 + p * 16;
            float4 v = *(const float4*)&W[(size_t)(bn + row) * 128 + k0 + q4 * 4];
            unsigned lo = f2bu(v.x) | ((unsigned)f2bu(v.y) << 16);
            unsigned hi = f2bu(v.z) | ((unsigned)f2bu(v.w) << 16);
            int off = (row * 128 + q4 * 8) ^ ((row & 7) << 4);
            *(uint2*)((char*)Ws + off) = make_uint2(lo, hi);
        }
        __syncthreads();
#pragma unroll
        for (int ks = 0; ks < 2; ++ks) {
            s16x8 a[4], b[2];
#pragma unroll
            for (int mf = 0; mf < 4; ++mf) {
                int row = wm * 64 + mf * 16 + l15;
                int off = (row * 256 + (k0 + ks * 32 + l4 * 8) * 2) ^ ((row & 7) << 4);
                a[mf] = *(const s16x8*)((const char*)Xs + off);
            }
#pragma unroll
            for (int nf = 0; nf < 2; ++nf) {
                int row = wn * 32 + nf * 16 + l15;
                int off = (row * 128 + (ks * 32 + l4 * 8) * 2) ^ ((row & 7) << 4);
                b[nf] = *(const s16x8*)((const char*)Ws + off);
            }
#pragma unroll
            for (int mf = 0; mf < 4; ++mf)
#pragma unroll
                for (int nf = 0; nf < 2; ++nf)
                    acc[mf][nf] = __builtin_amdgcn_mfma_f32_16x16x32_bf16(
                        a[mf], b[nf], acc[mf][nf], 0, 0, 0);
        }
        __syncthreads();
    }

#pragma unroll
    for (int mf = 0; mf < 4; ++mf) {
#pragma unroll
        for (int nf = 0; nf < 2; ++nf) {
            int col   = bn + wn * 32 + nf * 16 + l15;
            int rbase = bm + wm * 64 + mf * 16 + l4 * 4;
            float bv = BIAS ? bias[col] : 0.f;
#pragma unroll
            for (int r = 0; r < 4; ++r) {
                float v = acc[mf][nf][r] + bv;
                if (ACT == 2) v = 0.5f * v * (1.f + erff(v * 0.70710678118654752f));
                if (SPLIT) {
                    if (col < 256) Y [(size_t)(rbase + r) * 256 + col]       = v;
                    else           Y2[(size_t)(rbase + r) * 256 + col - 256] = v;
                } else {
                    Y[(size_t)(rbase + r) * N + col] = v;
                }
            }
        }
    }
}

// ---------------------------------------------------------------- dt+B/C GEMM (BM=64, BN=64, K=256)
// grid (128, 5) = 640 blocks. Blocks bn<4: dt = softplus(acc+bias) -> dtT[d][row], dtuT = dt*u.
// Block bn==4: cols 0..31 -> bct[n][row] (B rows 0..15, C rows 16..31).
__global__ __launch_bounds__(256) void mgemm_dtbc(
    const float* __restrict__ Xu, const float* __restrict__ W,
    const float* __restrict__ bias,
    float* __restrict__ dtT, float* __restrict__ dtuT, float* __restrict__ bct)
{
    __shared__ __align__(16) unsigned short Xs[64 * 64];
    __shared__ __align__(16) unsigned short Ws[64 * 64];
    int tid  = threadIdx.x;
    int lane = tid & 63;
    int wave = tid >> 6;
    int wm = wave >> 1, wn = wave & 1;
    int l15 = lane & 15, l4 = lane >> 4;
    int bm = blockIdx.x * 64, bn = blockIdx.y * 64;
    f32x4 acc[2][2] = {};
    int q  = tid & 15;
    int r0 = tid >> 4;

    for (int k0 = 0; k0 < 256; k0 += 64) {
        __syncthreads();
#pragma unroll
        for (int p = 0; p < 4; ++p) {
            int row = r0 + p * 16;
            float4 v = *(const float4*)&Xu[(size_t)(bm + row) * 256 + k0 + q * 4];
            unsigned lo = f2bu(v.x) | ((unsigned)f2bu(v.y) << 16);
            unsigned hi = f2bu(v.z) | ((unsigned)f2bu(v.w) << 16);
            int off = (row * 128 + q * 8) ^ ((row & 7) << 4);
            *(uint2*)((char*)Xs + off) = make_uint2(lo, hi);
        }
#pragma unroll
        for (int p = 0; p < 4; ++p) {
            int row = r0 + p * 16;
            float4 v = *(const float4*)&W[(size_t)(bn + row) * 256 + k0 + q * 4];
            unsigned lo = f2bu(v.x) | ((unsigned)f2bu(v.y) << 16);
            unsigned hi = f2bu(v.z) | ((unsigned)f2bu(v.w) << 16);
            int off = (row * 128 + q * 8) ^ ((row & 7) << 4);
            *(uint2*)((char*)Ws + off) = make_uint2(lo, hi);
        }
        __syncthreads();
#pragma unroll
        for (int ks = 0; ks < 2; ++ks) {
            s16x8 a[2], b[2];
#pragma unroll
            for (int mf = 0; mf < 2; ++mf) {
                int row = wm * 32 + mf * 16 + l15;
                int off = (row * 128 + (ks * 32 + l4 * 8) * 2) ^ ((row & 7) << 4);
                a[mf] = *(const s16x8*)((const char*)Xs + off);
            }
#pragma unroll
            for (int nf = 0; nf < 2; ++nf) {
                int row = wn * 32 + nf * 16 + l15;
                int off = (row * 128 + (ks * 32 + l4 * 8) * 2) ^ ((row & 7) << 4);
                b[nf] = *(const s16x8*)((const char*)Ws + off);
            }
#pragma unroll
            for (int mf = 0; mf < 2; ++mf)
#pragma unroll
                for (int nf = 0; nf < 2; ++nf)
                    acc[mf][nf] = __builtin_amdgcn_mfma_f32_16x16x32_bf16(
                        a[mf], b[nf], acc[mf][nf], 0, 0, 0);
        }
    }

    if (blockIdx.y < 4) {
#pragma unroll
        for (int mf = 0; mf < 2; ++mf) {
#pragma unroll
            for (int nf = 0; nf < 2; ++nf) {
                int col   = bn + wn * 32 + nf * 16 + l15;
                int rbase = bm + wm * 32 + mf * 16 + l4 * 4;
                float bv = bias[col];
                float4 uu;
                uu.x = Xu[(size_t)(rbase + 0) * 256 + col];
                uu.y = Xu[(size_t)(rbase + 1) * 256 + col];
                uu.z = Xu[(size_t)(rbase + 2) * 256 + col];
                uu.w = Xu[(size_t)(rbase + 3) * 256 + col];
                float v0 = softplus_f(acc[mf][nf][0] + bv);
                float v1 = softplus_f(acc[mf][nf][1] + bv);
                float v2 = softplus_f(acc[mf][nf][2] + bv);
                float v3 = softplus_f(acc[mf][nf][3] + bv);
                *(float4*)&dtT [(size_t)col * BLC + rbase] = make_float4(v0, v1, v2, v3);
                *(float4*)&dtuT[(size_t)col * BLC + rbase] =
                    make_float4(v0 * uu.x, v1 * uu.y, v2 * uu.z, v3 * uu.w);
            }
        }
    } else {
#pragma unroll
        for (int mf = 0; mf < 2; ++mf) {
#pragma unroll
            for (int nf = 0; nf < 2; ++nf) {
                int col16 = wn * 32 + nf * 16 + l15;     // 0..63, valid < 32
                int rbase = bm + wm * 32 + mf * 16 + l4 * 4;
                if (col16 < 32) {
                    *(float4*)&bct[(size_t)col16 * BLC + rbase] =
                        make_float4(acc[mf][nf][0], acc[mf][nf][1],
                                    acc[mf][nf][2], acc[mf][nf][3]);
                }
            }
        }
    }
}

// ---------------------------------------------------------------- conv1d (depthwise causal k=4) + silu
__global__ __launch_bounds__(256) void conv_silu_kernel(
    const float* __restrict__ u, const float* __restrict__ cw,
    const float* __restrict__ cb, float* __restrict__ out)
{
    int i   = blockIdx.x * 256 + threadIdx.x;   // BLC * 64
    int dq  = (i & 63) << 2;
    int row = i >> 6;
    int l   = row & (LSEQ - 1);
    float4 a = *(const float4*)&cb[dq];
    float w[4][4];
#pragma unroll
    for (int e = 0; e < 4; ++e) {
        float4 we = *(const float4*)&cw[(dq + e) * 4];
        w[e][0] = we.x; w[e][1] = we.y; w[e][2] = we.z; w[e][3] = we.w;
    }
#pragma unroll
    for (int j = 0; j < 4; ++j) {
        if (l >= 3 - j) {
            const float4 v = *(const float4*)&u[(size_t)(row - 3 + j) * 256 + dq];
            a.x = fmaf(v.x, w[0][j], a.x);
            a.y = fmaf(v.y, w[1][j], a.y);
            a.z = fmaf(v.z, w[2][j], a.z);
            a.w = fmaf(v.w, w[3][j], a.w);
        }
    }
    float4 o;
    o.x = a.x / (1.f + __expf(-a.x));
    o.y = a.y / (1.f + __expf(-a.y));
    o.z = a.z / (1.f + __expf(-a.z));
    o.w = a.w / (1.f + __expf(-a.w));
    *(float4*)&out[(size_t)row * 256 + dq] = o;
}

// ---------------------------------------------------------------- chunked selective scan
// Lane owns 4 n-states of one d: g = tid&3, dloc = tid>>2. grid (4, NC, B) = 1024 blocks.
__global__ __launch_bounds__(256) void scan_phase1(
    const float* __restrict__ dtT, const float* __restrict__ dtuT,
    const float* __restrict__ bct, const float* __restrict__ A_log,
    float* __restrict__ hend, float* __restrict__ aprod)
{
    int g    = threadIdx.x & 3;
    int dloc = threadIdx.x >> 2;
    int d    = blockIdx.x * 64 + dloc;
    int c    = blockIdx.y;
    int b    = blockIdx.z;
    float4 al = *(const float4*)&A_log[d * 16 + g * 4];
    float A0 = -__expf(al.x), A1 = -__expf(al.y), A2 = -__expf(al.z), A3 = -__expf(al.w);
    int base   = d * BLC + b * LSEQ + c * CHK;
    int btbase = b * LSEQ + c * CHK;
    const float* B0p = bct + (size_t)(g * 4 + 0) * BLC + btbase;
    const float* B1p = B0p + BLC;
    const float* B2p = B1p + BLC;
    const float* B3p = B2p + BLC;
    float h0 = 0.f, h1 = 0.f, h2 = 0.f, h3 = 0.f;
    float p0 = 1.f, p1 = 1.f, p2 = 1.f, p3 = 1.f;
#pragma unroll 2
    for (int t4 = 0; t4 < CHK; t4 += 4) {
        float4 dt4 = *(const float4*)&dtT [base + t4];
        float4 du4 = *(const float4*)&dtuT[base + t4];
        float4 B0 = *(const float4*)(B0p + t4);
        float4 B1 = *(const float4*)(B1p + t4);
        float4 B2 = *(const float4*)(B2p + t4);
        float4 B3 = *(const float4*)(B3p + t4);
        float dts[4] = {dt4.x, dt4.y, dt4.z, dt4.w};
        float dus[4] = {du4.x, du4.y, du4.z, du4.w};
        float b0[4] = {B0.x, B0.y, B0.z, B0.w};
        float b1[4] = {B1.x, B1.y, B1.z, B1.w};
        float b2[4] = {B2.x, B2.y, B2.z, B2.w};
        float b3[4] = {B3.x, B3.y, B3.z, B3.w};
#pragma unroll
        for (int j = 0; j < 4; ++j) {
            float a0 = __expf(dts[j] * A0), a1 = __expf(dts[j] * A1);
            float a2 = __expf(dts[j] * A2), a3 = __expf(dts[j] * A3);
            h0 = fmaf(a0, h0, dus[j] * b0[j]); p0 *= a0;
            h1 = fmaf(a1, h1, dus[j] * b1[j]); p1 *= a1;
            h2 = fmaf(a2, h2, dus[j] * b2[j]); p2 *= a2;
            h3 = fmaf(a3, h3, dus[j] * b3[j]); p3 *= a3;
        }
    }
    int ch = (b * 256 + d) * 16 + g * 4;
    *(float4*)&hend [c * NCH + ch] = make_float4(h0, h1, h2, h3);
    *(float4*)&aprod[c * NCH + ch] = make_float4(p0, p1, p2, p3);
}

// Serial prefix over chunks; h0 written in place of aprod. Coalesced [c][ch] layout. O(NC) total.
__global__ __launch_bounds__(256) void scan_phase2(
    const float* __restrict__ hend, float* __restrict__ apr_h0)
{
    int ch = blockIdx.x * 256 + threadIdx.x;   // NCH
    float h = 0.f;
#pragma unroll 4
    for (int c = 0; c < NC; ++c) {
        float ap = apr_h0[c * NCH + ch];
        float he = hend[c * NCH + ch];
        apr_h0[c * NCH + ch] = h;
        h = fmaf(ap, h, he);
    }
}

// Phase 3: read h0 from apr, recompute chunk + C-dot + write y[row][d].
__global__ __launch_bounds__(256) void scan_phase3(
    const float* __restrict__ dtT, const float* __restrict__ dtuT,
    const float* __restrict__ bct, const float* __restrict__ A_log,
    const float* __restrict__ h0b, float* __restrict__ y)
{
    int g    = threadIdx.x & 3;
    int dloc = threadIdx.x >> 2;
    int d    = blockIdx.x * 64 + dloc;
    int c    = blockIdx.y;
    int b    = blockIdx.z;
    float4 al = *(const float4*)&A_log[d * 16 + g * 4];
    float A0 = -__expf(al.x), A1 = -__expf(al.y), A2 = -__expf(al.z), A3 = -__expf(al.w);
    int ch = (b * 256 + d) * 16 + g * 4;
    float4 hv = *(const float4*)&h0b[c * NCH + ch];
    float h0 = hv.x, h1 = hv.y, h2 = hv.z, h3 = hv.w;
    int base = d * BLC + b * LSEQ + c * CHK;
    int row0 = b * LSEQ + c * CHK;
    const float* B0p = bct + (size_t)(g * 4 + 0) * BLC + row0;
    const float* B1p = B0p + BLC;
    const float* B2p = B1p + BLC;
    const float* B3p = B2p + BLC;
    const float* C0p = bct + (size_t)(16 + g * 4) * BLC + row0;
    const float* C1p = C0p + BLC;
    const float* C2p = C1p + BLC;
    const float* C3p = C2p + BLC;
#pragma unroll 2
    for (int t4 = 0; t4 < CHK; t4 += 4) {
        float4 dt4 = *(const float4*)&dtT [base + t4];
        float4 du4 = *(const float4*)&dtuT[base + t4];
        float4 B0 = *(const float4*)(B0p + t4);
        float4 B1 = *(const float4*)(B1p + t4);
        float4 B2 = *(const float4*)(B2p + t4);
        float4 B3 = *(const float4*)(B3p + t4);
        float4 C0 = *(const float4*)(C0p + t4);
        float4 C1 = *(const float4*)(C1p + t4);
        float4 C2 = *(const float4*)(C2p + t4);
        float4 C3 = *(const float4*)(C3p + t4);
        float dts[4] = {dt4.x, dt4.y, dt4.z, dt4.w};
        float dus[4] = {du4.x, du4.y, du4.z, du4.w};
        float b0[4] = {B0.x, B0.y, B0.z, B0.w};
        float b1[4] = {B1.x, B1.y, B1.z, B1.w};
        float b2[4] = {B2.x, B2.y, B2.z, B2.w};
        float b3[4] = {B3.x, B3.y, B3.z, B3.w};
        float c0[4] = {C0.x, C0.y, C0.z, C0.w};
        float c1[4] = {C1.x, C1.y, C1.z, C1.w};
        float c2[4] = {C2.x, C2.y, C2.z, C2.w};
        float c3[4] = {C3.x, C3.y, C3.z, C3.w};
#pragma unroll
        for (int j = 0; j < 4; ++j) {
            float a0 = __expf(dts[j] * A0), a1 = __expf(dts[j] * A1);
            float a2 = __expf(dts[j] * A2), a3 = __expf(dts[j] * A3);
            h0 = fmaf(a0, h0, dus[j] * b0[j]);
            h1 = fmaf(a1, h1, dus[j] * b1[j]);
            h2 = fmaf(a2, h2, dus[j] * b2[j]);
            h3 = fmaf(a3, h3, dus[j] * b3[j]);
            float p = h0 * c0[j];
            p = fmaf(h1, c1[j], p);
            p = fmaf(h2, c2[j], p);
            p = fmaf(h3, c3[j], p);
            p += __shfl_xor(p, 1);
            p += __shfl_xor(p, 2);
            if (g == 0) y[(size_t)(row0 + t4 + j) * 256 + d] = p;
        }
    }
}

// ---------------------------------------------------------------- launch
extern "C" void kernel_launch(void* const* d_in, const int* in_sizes, int n_in,
                              void* d_out, int out_size, void* d_ws, size_t ws_size,
                              hipStream_t stream)
{
    const float* x        = (const float*)d_in[0];
    const float* embed_w  = (const float*)d_in[1];
    const float* embed_b  = (const float*)d_in[2];
    const float* outc_w   = (const float*)d_in[3];
    const float* outc_b   = (const float*)d_in[4];
    const float* ln_g     = (const float*)d_in[5];
    const float* ln_b     = (const float*)d_in[6];
    const float* in_w     = (const float*)d_in[7];
    const float* conv_w   = (const float*)d_in[8];
    const float* conv_b   = (const float*)d_in[9];
    const float* xproj_w  = (const float*)d_in[10];
    const float* dtproj_w = (const float*)d_in[11];
    const float* dtproj_b = (const float*)d_in[12];
    const float* A_log    = (const float*)d_in[13];
    const float* ssm_D    = (const float*)d_in[14];
    const float* mout_w   = (const float*)d_in[15];
    const float* ffn_w1   = (const float*)d_in[16];
    const float* ffn_b1   = (const float*)d_in[17];
    const float* ffn_w2   = (const float*)d_in[18];
    const float* ffn_b2   = (const float*)d_in[19];

    float* ws    = (float*)d_ws;
    float* t     = ws;                  // (BLC,128)  1,048,576
    float* tmp2  = ws + 1048576;        // 2M: transpose-in out / dtuT
    float* ub    = ws + 3145728;        // 2M: u / dtT / ffn-mid lo
    float* zb    = ws + 5242880;        // 2M: z / ffn-mid hi
    float* ucv   = ws + 7340032;        // 2M: conv+silu out
    float* dtb   = ws + 9437184;        // 2M: y_scan
    float* bct   = ws + 11534336;       // [32][BLC]   262,144
    float* hend  = ws + 11796480;       // [NC][NCH] 1,048,576
    float* apr   = ws + 12845056;       // [NC][NCH] 1,048,576 -> h0
    float* wcomb = ws + 13893632;       // 2 x 384 x 256 = 196,608  (total ~56.4 MB)
    float* out   = (float*)d_out;

    float* dtT    = ub;
    float* dtuT   = tmp2;
    float* ffnmid = ub;                 // spans ub+zb (BLC x 512)

    dim3 tb(32, 8);
    build_wcomb<<<768, 256, 0, stream>>>(xproj_w, dtproj_w, wcomb);
    transpose_kernel<<<dim3(128, 4, 2), tb, 0, stream>>>(x, tmp2, 128, 4096);
    mgemm<64, 64, 0, true, false, false, false><<<dim3(128, 2), 256, 0, stream>>>(
        tmp2, embed_w, embed_b, nullptr, nullptr, nullptr, nullptr, t, 128, 128);

    for (int i = 0; i < 2; ++i) {
        mgemm_ln<0, false, true><<<dim3(64, 8), 256, 0, stream>>>(
            t, ln_g + i * 128, ln_b + i * 128, in_w + i * 65536, nullptr, ub, zb, 512);
        conv_silu_kernel<<<2048, 256, 0, stream>>>(ub, conv_w + i * 1024, conv_b + i * 256, ucv);
        mgemm_dtbc<<<dim3(128, 5), 256, 0, stream>>>(
            ucv, wcomb + i * 98304, dtproj_b + i * 256, dtT, dtuT, bct);
        scan_phase1<<<dim3(4, NC, 2), 256, 0, stream>>>(dtT, dtuT, bct, A_log + i * 4096, hend, apr);
        scan_phase2<<<32, 256, 0, stream>>>(hend, apr);
        scan_phase3<<<dim3(4, NC, 2), 256, 0, stream>>>(dtT, dtuT, bct, A_log + i * 4096, apr, dtb);
        mgemm<64, 64, 0, false, true, true, false><<<dim3(128, 2), 256, 0, stream>>>(
            dtb, mout_w + i * 32768, nullptr, t, ucv, zb, ssm_D + i * 256, t, 128, 256);
        mgemm_ln<2, true, false><<<dim3(64, 8), 256, 0, stream>>>(
            t, ln_g + i * 128, ln_b + i * 128, ffn_w1 + i * 65536, ffn_b1 + i * 512, ffnmid, nullptr, 512);
        mgemm<64, 64, 0, true, true, false, false><<<dim3(128, 2), 256, 0, stream>>>(
            ffnmid, ffn_w2 + i * 65536, ffn_b2 + i * 128, t, nullptr, nullptr, nullptr, t, 128, 512);
    }

    // outc fused with output transpose + residual-x add
    mgemm<64, 64, 0, true, false, false, true><<<dim3(128, 2), 256, 0, stream>>>(
        t, outc_w, outc_b, x, nullptr, nullptr, nullptr, out, 128, 128);
}